// Round 2
// baseline (46958.493 us; speedup 1.0000x reference)
//
#include <hip/hip_runtime.h>
#include <hip/hip_bf16.h>
#include <stdint.h>

// Problem dims (fixed by reference)
#define B_ 64
#define S_ 256
#define T_ 256
#define D_ 256
#define H_ 256
#define V_ 1000

__device__ __forceinline__ float sigm(float x){ return 1.0f / (1.0f + __expf(-x)); }
__device__ __forceinline__ float tanhfast(float x){ float e = __expf(2.0f * x); return 1.0f - 2.0f / (e + 1.0f); }

__device__ __forceinline__ void cellupd(float a0, float a1, float a2, float a3, float& c, float& h){
  // gate order: i=a0, f=a1, g=a2, o=a3
  float cn = sigm(a1) * c + sigm(a0) * tanhfast(a2);
  c = cn;
  h = sigm(a3) * tanhfast(cn);
}

__device__ __forceinline__ float wredmax(float v){
  #pragma unroll
  for (int o = 32; o > 0; o >>= 1) v = fmaxf(v, __shfl_xor(v, o));
  return v;
}
__device__ __forceinline__ float wredsum(float v){
  #pragma unroll
  for (int o = 32; o > 0; o >>= 1) v += __shfl_xor(v, o);
  return v;
}

// ---------------- dtype probe ----------------
// True-bf16 weights (|w|<1) have biased exponent <= 0x7D. If the buffer is
// really f32, half the shorts we scan are low mantissa halves of floats:
// uniform bits -> ~25% have "exponent" >= 0xC0. Count>32 ==> f32.
__global__ void probe_kernel(const unsigned short* __restrict__ w, int* __restrict__ flag)
{
  int cnt = 0;
  for (int i = threadIdx.x; i < 4096; i += 64) {
    unsigned e = (w[i] >> 7) & 0xFFu;
    if (e >= 0xC0u) cnt++;
  }
  #pragma unroll
  for (int o = 32; o > 0; o >>= 1) cnt += __shfl_xor(cnt, o);
  if (threadIdx.x == 0) *flag = (cnt > 32) ? 1 : 0;
}

__device__ __forceinline__ float load_any(const void* src, int i, int isf32){
  return isf32 ? ((const float*)src)[i]
               : __uint_as_float(((unsigned)((const unsigned short*)src)[i]) << 16);
}

// plain convert (either dtype) -> f32
__global__ void conv_kernel(const void* __restrict__ src, float* __restrict__ dst, int n,
                            const int* __restrict__ flagp)
{
  int i = blockIdx.x * 256 + threadIdx.x;
  if (i >= n) return;
  dst[i] = load_any(src, i, *flagp);
}

// Swizzled f32 weight layout for an (R x K) matrix:
//   swzf[ (((r>>6)*(K>>2) + (k>>2))*64 + (r&63))*4 + (k&3) ] = W[r][k]
// Hot-loop read: lane (r&63) loads float4 at consecutive lane addresses -> 1KB/wave coalesced.
__global__ void swzf_kernel(const void* __restrict__ src, float* __restrict__ dst,
                            int R, int Ks, int Kt, int c0, const int* __restrict__ flagp)
{
  int i = blockIdx.x * 256 + threadIdx.x;
  if (i >= R * Ks) return;
  int r = i / Ks;
  int k = i - r * Ks;
  int kk = k + c0;
  float v = load_any(src, i, *flagp);
  dst[(((size_t)(r >> 6) * (size_t)(Kt >> 2) + (size_t)(kk >> 2)) * 64 + (r & 63)) * 4 + (kk & 3)] = v;
}

// 4-gate-row fused dot: rows j, j+256, j+512, j+768 of a (1024 x K) swizzled matrix, x in LDS.
template<int K>
__device__ __forceinline__ void dot4f(const float* __restrict__ w, int j,
                                      const float* __restrict__ xs,
                                      float& a0, float& a1, float& a2, float& a3)
{
  constexpr int KC = K >> 2;
  const int lane = j & 63;
  const int wq = j >> 6;
  const float4* __restrict__ p0 = (const float4*)w + (size_t)(wq     ) * KC * 64 + lane;
  const float4* __restrict__ p1 = (const float4*)w + (size_t)(wq + 4 ) * KC * 64 + lane;
  const float4* __restrict__ p2 = (const float4*)w + (size_t)(wq + 8 ) * KC * 64 + lane;
  const float4* __restrict__ p3 = (const float4*)w + (size_t)(wq + 12) * KC * 64 + lane;
  #pragma unroll 4
  for (int kc = 0; kc < KC; ++kc) {
    const float4 x = *(const float4*)(xs + kc * 4);
    float4 q;
    q = p0[(size_t)kc * 64]; a0 += q.x*x.x + q.y*x.y + q.z*x.z + q.w*x.w;
    q = p1[(size_t)kc * 64]; a1 += q.x*x.x + q.y*x.y + q.z*x.z + q.w*x.w;
    q = p2[(size_t)kc * 64]; a2 += q.x*x.x + q.y*x.y + q.z*x.z + q.w*x.w;
    q = p3[(size_t)kc * 64]; a3 += q.x*x.x + q.y*x.y + q.z*x.z + q.w*x.w;
  }
}

template<int K>
__device__ __forceinline__ float dot1f(const float* __restrict__ w, int r,
                                       const float* __restrict__ xs)
{
  constexpr int KC = K >> 2;
  const float4* __restrict__ p = (const float4*)w + (size_t)(r >> 6) * KC * 64 + (r & 63);
  float a = 0.0f;
  #pragma unroll 4
  for (int kc = 0; kc < KC; ++kc) {
    const float4 q = p[(size_t)kc * 64];
    const float4 x = *(const float4*)(xs + kc * 4);
    a += q.x*x.x + q.y*x.y + q.z*x.z + q.w*x.w;
  }
  return a;
}

// Encoder layer 0: 128 blocks = (dir*64 + b). Cat weight [Wih(256)|Whh(256)] -> K=512.
__global__ __launch_bounds__(256) void enc0_kernel(
    const int* __restrict__ src, const float* __restrict__ emb_f,
    const float* __restrict__ wF, const float* __restrict__ wB,
    const float* __restrict__ bF, const float* __restrict__ bB,  // pre-summed bih+bhh, 1024 each
    float* __restrict__ f0, float* __restrict__ b0)
{
  const int blk = blockIdx.x, dir = blk >> 6, b = blk & 63, j = threadIdx.x;
  const float* w = dir ? wB : wF;
  const float* bi = dir ? bB : bF;
  float* outp = dir ? b0 : f0;
  __shared__ __align__(16) float xs[512];
  float bias[4];
  #pragma unroll
  for (int g = 0; g < 4; ++g) bias[g] = bi[j + g * 256];
  float c = 0.0f, h = 0.0f;
  const size_t bS = (size_t)b * S_;
  for (int t = 0; t < S_; ++t) {
    const int tp = dir ? (S_ - 1 - t) : t;
    const int tok = src[bS + tp];
    xs[j]       = emb_f[(size_t)tok * D_ + j];
    xs[256 + j] = h;
    __syncthreads();
    float a0 = bias[0], a1 = bias[1], a2 = bias[2], a3 = bias[3];
    dot4f<512>(w, j, xs, a0, a1, a2, a3);
    cellupd(a0, a1, a2, a3, c, h);
    outp[(bS + tp) * H_ + j] = h;
    __syncthreads();
  }
}

// Encoder layer 1: input [f0|b0](512) + h(256) -> K=768. Also emits final (h,c) per dir.
__global__ __launch_bounds__(256) void enc1_kernel(
    const float* __restrict__ f0, const float* __restrict__ b0,
    const float* __restrict__ wF, const float* __restrict__ wB,
    const float* __restrict__ bF, const float* __restrict__ bB,
    float* __restrict__ enc_out, float* __restrict__ hcbuf)
{
  const int blk = blockIdx.x, dir = blk >> 6, b = blk & 63, j = threadIdx.x;
  const float* w = dir ? wB : wF;
  const float* bi = dir ? bB : bF;
  __shared__ __align__(16) float xs[768];
  float bias[4];
  #pragma unroll
  for (int g = 0; g < 4; ++g) bias[g] = bi[j + g * 256];
  float c = 0.0f, h = 0.0f;
  const size_t bS = (size_t)b * S_;
  for (int t = 0; t < S_; ++t) {
    const int tp = dir ? (S_ - 1 - t) : t;
    const size_t row = (bS + tp) * (size_t)H_;
    xs[j]       = f0[row + j];
    xs[256 + j] = b0[row + j];
    xs[512 + j] = h;
    __syncthreads();
    float a0 = bias[0], a1 = bias[1], a2 = bias[2], a3 = bias[3];
    dot4f<768>(w, j, xs, a0, a1, a2, a3);
    cellupd(a0, a1, a2, a3, c, h);
    enc_out[(bS + tp) * 512 + dir * 256 + j] = h;
    __syncthreads();
  }
  const int BH = B_ * H_;
  float* hout = hcbuf + (dir ? 2 * BH : 0);
  hout[(size_t)b * H_ + j]      = h;
  hout[BH + (size_t)b * H_ + j] = c;
}

// blocks [0,1024): epT[b][j][s] = sum_k enc_out[b][s][k]*Wenc[j][k]  (transposed in s)
// blocks [1024,1088): h0/c0 projections
__global__ __launch_bounds__(256) void proj_kernel(
    const float* __restrict__ enc_out, const float* __restrict__ hcbuf,
    const float* __restrict__ wenc_s,
    const float* __restrict__ hpw_s, const float* __restrict__ cpw_s,
    const float* __restrict__ hpb_f, const float* __restrict__ cpb_f,
    float* __restrict__ epT, float* __restrict__ h0c0)
{
  __shared__ __align__(16) float xs[16 * 512];
  const int blk = blockIdx.x, tid = threadIdx.x;
  if (blk < 1024) {
    const int b = blk >> 4, s0 = (blk & 15) * 16;
    const float* srcp = enc_out + ((size_t)b * S_ + s0) * 512;
    for (int i = tid; i < 16 * 512; i += 256) xs[i] = srcp[i];
    __syncthreads();
    float acc[16];
    #pragma unroll
    for (int r = 0; r < 16; ++r) acc[r] = 0.0f;
    const float4* p = (const float4*)wenc_s + (size_t)(tid >> 6) * 128 * 64 + (tid & 63); // KC=128
    for (int kc = 0; kc < 128; ++kc) {
      const float4 q = p[(size_t)kc * 64];
      #pragma unroll
      for (int r = 0; r < 16; ++r) {
        const float4 x = *(const float4*)(xs + r * 512 + kc * 4);
        acc[r] += q.x*x.x + q.y*x.y + q.z*x.z + q.w*x.w;
      }
    }
    float* dst = epT + ((size_t)b * S_ + (size_t)tid) * 256 + s0;
    #pragma unroll
    for (int r = 0; r < 16; ++r) dst[r] = acc[r];
  } else {
    const int b = blk - 1024;
    const int BH = B_ * H_;
    xs[tid]        = hcbuf[(size_t)b * H_ + tid];            // hf
    xs[256 + tid]  = hcbuf[2 * BH + (size_t)b * H_ + tid];   // hb
    xs[512 + tid]  = hcbuf[BH + (size_t)b * H_ + tid];       // cf
    xs[768 + tid]  = hcbuf[3 * BH + (size_t)b * H_ + tid];   // cb
    __syncthreads();
    const float hv = dot1f<512>(hpw_s, tid, xs)       + hpb_f[tid];
    const float cv = dot1f<512>(cpw_s, tid, xs + 512) + cpb_f[tid];
    h0c0[(size_t)b * H_ + tid]              = tanhfast(hv);
    h0c0[(size_t)BH + (size_t)b * H_ + tid] = tanhfast(cv);
  }
}

// Decoder: one block per batch element; all 256 steps in-block.
__global__ __launch_bounds__(256) void dec_kernel(
    const int* __restrict__ src, const int* __restrict__ tgt, const float* __restrict__ emb_f,
    const float* __restrict__ d0_s, const float* __restrict__ d1_s,
    const float* __restrict__ wdec_s,
    const float* __restrict__ d0b, const float* __restrict__ d1b,  // pre-summed biases
    const float* __restrict__ attv_f,
    const float* __restrict__ enc_out, const float* __restrict__ epT,
    const float* __restrict__ h0c0,
    float* __restrict__ dec_h)
{
  const int b = blockIdx.x, j = threadIdx.x;
  __shared__ __align__(16) float xcat[1024];  // [xt(256) | ctx(512) | hl0(256)]
  __shared__ __align__(16) float hcat[512];   // [hl0(256) | hl1(256)]
  __shared__ __align__(16) float qs[256];
  __shared__ __align__(16) float sc[256];
  __shared__ __align__(16) float vv[256];
  __shared__ __align__(16) float mb[256];
  __shared__ float red[8];

  const float h0v = h0c0[(size_t)b * H_ + j];
  const float c0v = h0c0[(size_t)B_ * H_ + (size_t)b * H_ + j];
  float cl0 = c0v, cl1 = c0v;
  float b00 = d0b[j], b01 = d0b[j + 256], b02 = d0b[j + 512], b03 = d0b[j + 768];
  float b10 = d1b[j], b11 = d1b[j + 256], b12 = d1b[j + 512], b13 = d1b[j + 768];
  xcat[768 + j] = h0v;
  hcat[j]       = h0v;
  hcat[256 + j] = h0v;
  vv[j] = attv_f[j];
  mb[j] = (src[(size_t)b * S_ + j] == 0) ? -1e30f : 0.0f;
  __syncthreads();

  const float* eo = enc_out + (size_t)b * S_ * 512 + j;
  const float* ep = epT + (size_t)b * 65536 + j;
  const int wid = j >> 6;

  for (int t = 0; t < T_; ++t) {
    // ---- attention query q = hl1 @ Wdec.T
    const float q = dot1f<256>(wdec_s, j, hcat + 256);
    qs[j] = q;
    __syncthreads();
    // ---- score for s = j  (epT is [b][jj][s]: lane-coalesced)
    float e = 0.0f;
    #pragma unroll 4
    for (int jj = 0; jj < 256; ++jj)
      e += vv[jj] * tanhfast(ep[(size_t)jj * 256] + qs[jj]);
    e += mb[j];
    // ---- softmax over s
    float m = wredmax(e);
    if ((j & 63) == 0) red[wid] = m;
    __syncthreads();
    m = fmaxf(fmaxf(red[0], red[1]), fmaxf(red[2], red[3]));
    const float pexp = __expf(e - m);
    float sm = wredsum(pexp);
    if ((j & 63) == 0) red[4 + wid] = sm;
    __syncthreads();
    sm = (red[4] + red[5]) + (red[6] + red[7]);
    sc[j] = pexp / sm;
    __syncthreads();
    // ---- ctx = w @ enc_out (coalesced over j) + xt embed
    float ca = 0.0f, cbv = 0.0f;
    #pragma unroll 4
    for (int s = 0; s < 256; ++s) {
      const float w_ = sc[s];
      ca  += w_ * eo[(size_t)s * 512];
      cbv += w_ * eo[(size_t)s * 512 + 256];
    }
    const int tok = tgt[(size_t)b * 257 + t];
    xcat[j]       = emb_f[(size_t)tok * 256 + j];
    xcat[256 + j] = ca;
    xcat[512 + j] = cbv;
    __syncthreads();
    // ---- decoder cell 0: gates over [xt|ctx|hl0] (K=1024)
    float a0 = b00, a1 = b01, a2 = b02, a3 = b03;
    dot4f<1024>(d0_s, j, xcat, a0, a1, a2, a3);
    float hn0; cellupd(a0, a1, a2, a3, cl0, hn0);
    __syncthreads();
    hcat[j]       = hn0;
    xcat[768 + j] = hn0;
    __syncthreads();
    // ---- decoder cell 1: gates over [hl0|hl1] (K=512)
    a0 = b10; a1 = b11; a2 = b12; a3 = b13;
    dot4f<512>(d1_s, j, hcat, a0, a1, a2, a3);
    float hn1; cellupd(a0, a1, a2, a3, cl1, hn1);
    __syncthreads();
    hcat[256 + j] = hn1;
    dec_h[((size_t)b * T_ + t) * H_ + j] = hn1;
    __syncthreads();
  }
}

// Final logits: out[row][v] = dec_h[row] . emb[v]  (1024 blocks x 16 rows). Output dtype per flag.
__global__ __launch_bounds__(256) void out_kernel(
    const float* __restrict__ dec_h, const float* __restrict__ emb_s,
    void* __restrict__ out, const int* __restrict__ flagp)
{
  __shared__ __align__(16) float hs[16 * 256];
  const int blk = blockIdx.x, tid = threadIdx.x;
  const int isf32 = *flagp;
  const float* srcp = dec_h + (size_t)blk * (16 * 256);
  for (int i = tid; i < 16 * 256; i += 256) hs[i] = srcp[i];
  __syncthreads();
  const int lane = tid & 63;
  #pragma unroll
  for (int vi = 0; vi < 4; ++vi) {
    const int v = tid + vi * 256;
    if (v < V_) {
      const float4* p = (const float4*)emb_s + (size_t)(v >> 6) * 64 * 64 + lane; // KC=64
      float acc[16];
      #pragma unroll
      for (int r = 0; r < 16; ++r) acc[r] = 0.0f;
      for (int kc = 0; kc < 64; ++kc) {
        const float4 q = p[(size_t)kc * 64];
        #pragma unroll
        for (int r = 0; r < 16; ++r) {
          const float4 x = *(const float4*)(hs + r * 256 + kc * 4);
          acc[r] += q.x*x.x + q.y*x.y + q.z*x.z + q.w*x.w;
        }
      }
      const size_t rowbase = (size_t)blk * 16;
      if (isf32) {
        float* o = (float*)out;
        #pragma unroll
        for (int r = 0; r < 16; ++r) o[(rowbase + r) * V_ + v] = acc[r];
      } else {
        __hip_bfloat16* o = (__hip_bfloat16*)out;
        #pragma unroll
        for (int r = 0; r < 16; ++r) o[(rowbase + r) * V_ + v] = __float2bfloat16(acc[r]);
      }
    }
  }
}

// sum two converted bias vectors: dst[i] = a[i] + b[i] (from either dtype)
__global__ void bias_kernel(const void* __restrict__ a, const void* __restrict__ bsrc,
                            float* __restrict__ dst, int n, const int* __restrict__ flagp)
{
  int i = blockIdx.x * 256 + threadIdx.x;
  if (i >= n) return;
  int f = *flagp;
  dst[i] = load_any(a, i, f) + load_any(bsrc, i, f);
}

extern "C" void kernel_launch(void* const* d_in, const int* in_sizes, int n_in,
                              void* d_out, int out_size, void* d_ws, size_t ws_size,
                              hipStream_t stream)
{
  (void)in_sizes; (void)n_in; (void)out_size; (void)ws_size;
  const int* src = (const int*)d_in[0];
  const int* tgt = (const int*)d_in[1];

  // -------- workspace layout: flag | f32 activations | f32 biases | f32 swizzled weights (~88 MB)
  char* base = (char*)d_ws;
  int* flag = (int*)base;
  float* ws = (float*)(base + 256);
  size_t off = 0;
  float* f0      = ws + off; off += (size_t)B_ * S_ * H_;       // 16.8 MB (reused as dec_h)
  float* b0      = ws + off; off += (size_t)B_ * S_ * H_;       // 16.8 MB (reused as epT)
  float* enc_out = ws + off; off += (size_t)B_ * S_ * 2 * H_;   // 33.6 MB
  float* hcbuf   = ws + off; off += 4 * (size_t)B_ * H_;
  float* h0c0    = ws + off; off += 2 * (size_t)B_ * H_;
  float* emb_f   = ws + off; off += (size_t)V_ * D_;            // 1.0 MB plain f32 emb
  float* e0f_b   = ws + off; off += 1024;
  float* e0b_b   = ws + off; off += 1024;
  float* e1f_b   = ws + off; off += 1024;
  float* e1b_b   = ws + off; off += 1024;
  float* d0_b    = ws + off; off += 1024;
  float* d1_b    = ws + off; off += 1024;
  float* hpb_f   = ws + off; off += 256;
  float* cpb_f   = ws + off; off += 256;
  float* attv_f  = ws + off; off += 256;
  float* e0f_s   = ws + off; off += (size_t)1024 * 512;
  float* e0b_s   = ws + off; off += (size_t)1024 * 512;
  float* e1f_s   = ws + off; off += (size_t)1024 * 768;
  float* e1b_s   = ws + off; off += (size_t)1024 * 768;
  float* d0_s    = ws + off; off += (size_t)1024 * 1024;
  float* d1_s    = ws + off; off += (size_t)1024 * 512;
  float* wdec_s  = ws + off; off += (size_t)256 * 256;
  float* wenc_s  = ws + off; off += (size_t)256 * 512;
  float* hpw_s   = ws + off; off += (size_t)256 * 512;
  float* cpw_s   = ws + off; off += (size_t)256 * 512;
  float* emb_s   = ws + off; off += (size_t)1024 * 256;
  float* dec_h = f0;   // aliases: f0 dead after enc1
  float* epT   = b0;   // b0 dead after enc1

  hipLaunchKernelGGL(probe_kernel, dim3(1), dim3(64), 0, stream,
                     (const unsigned short*)d_in[3], flag);

  auto swz = [&](int idx, float* dst, int R, int Ks, int Kt, int c0){
    const int n = R * Ks;
    hipLaunchKernelGGL(swzf_kernel, dim3((n + 255) / 256), dim3(256), 0, stream,
                       d_in[idx], dst, R, Ks, Kt, c0, flag);
  };
  auto bias2 = [&](int ia, int ib, float* dst, int n){
    hipLaunchKernelGGL(bias_kernel, dim3((n + 255) / 256), dim3(256), 0, stream,
                       d_in[ia], d_in[ib], dst, n, flag);
  };

  // plain conversions
  hipLaunchKernelGGL(conv_kernel, dim3((V_ * D_ + 255) / 256), dim3(256), 0, stream,
                     d_in[2], emb_f, V_ * D_, flag);
  hipLaunchKernelGGL(conv_kernel, dim3(1), dim3(256), 0, stream, d_in[28], hpb_f, 256, flag);
  hipLaunchKernelGGL(conv_kernel, dim3(1), dim3(256), 0, stream, d_in[30], cpb_f, 256, flag);
  hipLaunchKernelGGL(conv_kernel, dim3(1), dim3(256), 0, stream, d_in[33], attv_f, 256, flag);
  // pre-summed biases (bih + bhh)
  bias2(5, 6, e0f_b, 1024);   bias2(9, 10, e0b_b, 1024);
  bias2(13, 14, e1f_b, 1024); bias2(17, 18, e1b_b, 1024);
  bias2(21, 22, d0_b, 1024);  bias2(25, 26, d1_b, 1024);
  // swizzled cat weights [Wih | Whh]
  swz(3,  e0f_s, 1024, 256, 512, 0);   swz(4,  e0f_s, 1024, 256, 512, 256);
  swz(7,  e0b_s, 1024, 256, 512, 0);   swz(8,  e0b_s, 1024, 256, 512, 256);
  swz(11, e1f_s, 1024, 512, 768, 0);   swz(12, e1f_s, 1024, 256, 768, 512);
  swz(15, e1b_s, 1024, 512, 768, 0);   swz(16, e1b_s, 1024, 256, 768, 512);
  swz(19, d0_s, 1024, 768, 1024, 0);   swz(20, d0_s, 1024, 256, 1024, 768);
  swz(23, d1_s, 1024, 256, 512, 0);    swz(24, d1_s, 1024, 256, 512, 256);
  swz(32, wdec_s, 256, 256, 256, 0);
  swz(31, wenc_s, 256, 512, 512, 0);
  swz(27, hpw_s, 256, 512, 512, 0);
  swz(29, cpw_s, 256, 512, 512, 0);
  swz(2,  emb_s, 1000, 256, 256, 0);

  hipLaunchKernelGGL(enc0_kernel, dim3(128), dim3(256), 0, stream,
                     src, emb_f, e0f_s, e0b_s, e0f_b, e0b_b, f0, b0);
  hipLaunchKernelGGL(enc1_kernel, dim3(128), dim3(256), 0, stream,
                     f0, b0, e1f_s, e1b_s, e1f_b, e1b_b, enc_out, hcbuf);
  hipLaunchKernelGGL(proj_kernel, dim3(1088), dim3(256), 0, stream,
                     enc_out, hcbuf, wenc_s, hpw_s, cpw_s, hpb_f, cpb_f, epT, h0c0);
  hipLaunchKernelGGL(dec_kernel, dim3(64), dim3(256), 0, stream,
                     src, tgt, emb_f, d0_s, d1_s, wdec_s, d0_b, d1_b, attv_f,
                     enc_out, epT, h0c0, dec_h);
  hipLaunchKernelGGL(out_kernel, dim3(1024), dim3(256), 0, stream,
                     dec_h, emb_s, d_out, flag);
}

// Round 3
// 28810.452 us; speedup vs baseline: 1.6299x; 1.6299x over previous
//
#include <hip/hip_runtime.h>
#include <hip/hip_bf16.h>
#include <stdint.h>

#define B_ 64
#define S_ 256
#define T_ 256
#define D_ 256
#define H_ 256
#define V_ 1000

__device__ __forceinline__ float blo(unsigned u){ return __uint_as_float(u << 16); }
__device__ __forceinline__ float bhi(unsigned u){ return __uint_as_float(u & 0xffff0000u); }
__device__ __forceinline__ float sigm(float x){ return 1.0f / (1.0f + __expf(-x)); }
__device__ __forceinline__ float tanhfast(float x){ float e = __expf(2.0f * x); return 1.0f - 2.0f / (e + 1.0f); }

__device__ __forceinline__ void cellupd(float a0, float a1, float a2, float a3, float& c, float& h){
  float cn = sigm(a1) * c + sigm(a0) * tanhfast(a2);
  c = cn;
  h = sigm(a3) * tanhfast(cn);
}

__device__ __forceinline__ float wredmax(float v){
  #pragma unroll
  for (int o = 32; o > 0; o >>= 1) v = fmaxf(v, __shfl_xor(v, o));
  return v;
}
__device__ __forceinline__ float wredsum(float v){
  #pragma unroll
  for (int o = 32; o > 0; o >>= 1) v += __shfl_xor(v, o);
  return v;
}

// ---------------- dtype probe (kept from round 2 — it works) ----------------
__global__ void probe_kernel(const unsigned short* __restrict__ w, int* __restrict__ flag)
{
  int cnt = 0;
  for (int i = threadIdx.x; i < 4096; i += 64) {
    unsigned e = (w[i] >> 7) & 0xFFu;
    if (e >= 0xC0u) cnt++;
  }
  #pragma unroll
  for (int o = 32; o > 0; o >>= 1) cnt += __shfl_xor(cnt, o);
  if (threadIdx.x == 0) *flag = (cnt > 32) ? 1 : 0;
}

__device__ __forceinline__ float load_any(const void* src, int i, int isf32){
  return isf32 ? ((const float*)src)[i]
               : __uint_as_float(((unsigned)((const unsigned short*)src)[i]) << 16);
}

__global__ void conv_kernel(const void* __restrict__ src, float* __restrict__ dst, int n,
                            const int* __restrict__ flagp)
{
  int i = blockIdx.x * 256 + threadIdx.x;
  if (i >= n) return;
  dst[i] = load_any(src, i, *flagp);
}

__global__ void bias_kernel(const void* __restrict__ a, const void* __restrict__ bsrc,
                            float* __restrict__ dst, int n, const int* __restrict__ flagp)
{
  int i = blockIdx.x * 256 + threadIdx.x;
  if (i >= n) return;
  int f = *flagp;
  dst[i] = load_any(a, i, f) + load_any(bsrc, i, f);
}

// Swizzled bf16 weight layout for an (R x K) matrix:
//   swz[ (((r>>6)*(K>>3) + (k>>3))*64 + (r&63))*8 + (k&7) ] = bf16(W[r][k])
// Hot loop: lane (r&63) loads uint4 (8 bf16) at consecutive lane addrs -> 1KB/wave.
// Exact when inputs are bf16 (f32->bf16 RN of an exact bf16 value is identity).
__global__ void swzb_kernel(const void* __restrict__ src, unsigned short* __restrict__ dst,
                            int R, int Ks, int Kt, int c0, const int* __restrict__ flagp)
{
  int i = blockIdx.x * 256 + threadIdx.x;
  if (i >= R * Ks) return;
  int r = i / Ks;
  int k = i - r * Ks;
  int kk = k + c0;
  float v = load_any(src, i, *flagp);
  __hip_bfloat16 bv = __float2bfloat16(v);
  dst[(((size_t)(r >> 6) * (size_t)(Kt >> 3) + (size_t)(kk >> 3)) * 64 + (r & 63)) * 8 + (kk & 7)] =
      *(unsigned short*)&bv;
}

// one full row r of an (R x K) swizzled bf16 matrix, x in LDS
template<int K>
__device__ __forceinline__ float dot1w(const unsigned short* __restrict__ w, int r,
                                       const float* __restrict__ xs)
{
  constexpr int KC = K >> 3;
  const uint4* __restrict__ p = (const uint4*)w + (size_t)(r >> 6) * KC * 64 + (r & 63);
  float a = 0.0f;
  #pragma unroll 4
  for (int kc = 0; kc < KC; ++kc) {
    const uint4 q = p[(size_t)kc * 64];
    const float4 x0 = *(const float4*)(xs + kc * 8);
    const float4 x1 = *(const float4*)(xs + kc * 8 + 4);
    a += blo(q.x)*x0.x + bhi(q.x)*x0.y + blo(q.y)*x0.z + bhi(q.y)*x0.w
       + blo(q.z)*x1.x + bhi(q.z)*x1.y + blo(q.w)*x1.z + bhi(q.w)*x1.w;
  }
  return a;
}

// Encoder layer 0: 128 blocks x 1024 threads. Cat weight [Wih|Whh] K=512. Thread = gate row.
__global__ __launch_bounds__(1024, 1) void enc0_kernel(
    const int* __restrict__ src, const float* __restrict__ emb_f,
    const unsigned short* __restrict__ wF, const unsigned short* __restrict__ wB,
    const float* __restrict__ bF, const float* __restrict__ bB,
    float* __restrict__ f0, float* __restrict__ b0)
{
  const int blk = blockIdx.x, dir = blk >> 6, b = blk & 63, tid = threadIdx.x;
  const unsigned short* w = dir ? wB : wF;
  const float* bi = dir ? bB : bF;
  float* outp = dir ? b0 : f0;
  __shared__ __align__(16) float xs[512];
  __shared__ __align__(16) float gates[1024];
  const float bias = bi[tid];
  float c = 0.0f, h = 0.0f;
  if (tid < 256) xs[256 + tid] = 0.0f;
  const size_t bS = (size_t)b * S_;
  for (int t = 0; t < S_; ++t) {
    const int tp = dir ? (S_ - 1 - t) : t;
    const int tok = src[bS + tp];
    if (tid < 256) xs[tid] = emb_f[(size_t)tok * D_ + tid];
    __syncthreads();
    gates[tid] = bias + dot1w<512>(w, tid, xs);
    __syncthreads();
    if (tid < 256) {
      cellupd(gates[tid], gates[tid + 256], gates[tid + 512], gates[tid + 768], c, h);
      xs[256 + tid] = h;
      outp[(bS + tp) * H_ + tid] = h;
    }
    __syncthreads();
  }
}

// Encoder layer 1: input [f0|b0|h] K=768. Emits final (h,c) per dir.
__global__ __launch_bounds__(1024, 1) void enc1_kernel(
    const float* __restrict__ f0, const float* __restrict__ b0,
    const unsigned short* __restrict__ wF, const unsigned short* __restrict__ wB,
    const float* __restrict__ bF, const float* __restrict__ bB,
    float* __restrict__ enc_out, float* __restrict__ hcbuf)
{
  const int blk = blockIdx.x, dir = blk >> 6, b = blk & 63, tid = threadIdx.x;
  const unsigned short* w = dir ? wB : wF;
  const float* bi = dir ? bB : bF;
  __shared__ __align__(16) float xs[768];
  __shared__ __align__(16) float gates[1024];
  const float bias = bi[tid];
  float c = 0.0f, h = 0.0f;
  if (tid < 256) xs[512 + tid] = 0.0f;
  const size_t bS = (size_t)b * S_;
  for (int t = 0; t < S_; ++t) {
    const int tp = dir ? (S_ - 1 - t) : t;
    const size_t row = (bS + tp) * (size_t)H_;
    if (tid < 512) {
      const int jj = tid & 255;
      xs[tid] = (tid < 256) ? f0[row + jj] : b0[row + jj];
    }
    __syncthreads();
    gates[tid] = bias + dot1w<768>(w, tid, xs);
    __syncthreads();
    if (tid < 256) {
      cellupd(gates[tid], gates[tid + 256], gates[tid + 512], gates[tid + 768], c, h);
      xs[512 + tid] = h;
      enc_out[(bS + tp) * 512 + dir * 256 + tid] = h;
    }
    __syncthreads();
  }
  if (tid < 256) {
    const int BH = B_ * H_;
    float* hout = hcbuf + (dir ? 2 * BH : 0);
    hout[(size_t)b * H_ + tid]      = h;
    hout[BH + (size_t)b * H_ + tid] = c;
  }
}

// blocks [0,1024): epT[b][j][s] (transposed in s); blocks [1024,1088): h0/c0 projections
__global__ __launch_bounds__(256) void proj_kernel(
    const float* __restrict__ enc_out, const float* __restrict__ hcbuf,
    const unsigned short* __restrict__ wenc_s,
    const unsigned short* __restrict__ hpw_s, const unsigned short* __restrict__ cpw_s,
    const float* __restrict__ hpb_f, const float* __restrict__ cpb_f,
    float* __restrict__ epT, float* __restrict__ h0c0)
{
  __shared__ __align__(16) float xs[16 * 512];
  const int blk = blockIdx.x, tid = threadIdx.x;
  if (blk < 1024) {
    const int b = blk >> 4, s0 = (blk & 15) * 16;
    const float* srcp = enc_out + ((size_t)b * S_ + s0) * 512;
    for (int i = tid; i < 16 * 512; i += 256) xs[i] = srcp[i];
    __syncthreads();
    float acc[16];
    #pragma unroll
    for (int r = 0; r < 16; ++r) acc[r] = 0.0f;
    const uint4* p = (const uint4*)wenc_s + (size_t)(tid >> 6) * 64 * 64 + (tid & 63); // KC=64
    for (int kc = 0; kc < 64; ++kc) {
      const uint4 q = p[(size_t)kc * 64];
      const float w0=blo(q.x), w1=bhi(q.x), w2=blo(q.y), w3=bhi(q.y),
                  w4=blo(q.z), w5=bhi(q.z), w6=blo(q.w), w7=bhi(q.w);
      #pragma unroll
      for (int r = 0; r < 16; ++r) {
        const float4 x0 = *(const float4*)(xs + r * 512 + kc * 8);
        const float4 x1 = *(const float4*)(xs + r * 512 + kc * 8 + 4);
        acc[r] += w0*x0.x + w1*x0.y + w2*x0.z + w3*x0.w + w4*x1.x + w5*x1.y + w6*x1.z + w7*x1.w;
      }
    }
    float* dst = epT + ((size_t)b * S_ + (size_t)tid) * 256 + s0;
    #pragma unroll
    for (int r = 0; r < 16; ++r) dst[r] = acc[r];
  } else {
    const int b = blk - 1024;
    const int BH = B_ * H_;
    xs[tid]        = hcbuf[(size_t)b * H_ + tid];            // hf
    xs[256 + tid]  = hcbuf[2 * BH + (size_t)b * H_ + tid];   // hb
    xs[512 + tid]  = hcbuf[BH + (size_t)b * H_ + tid];       // cf
    xs[768 + tid]  = hcbuf[3 * BH + (size_t)b * H_ + tid];   // cb
    __syncthreads();
    const float hv = dot1w<512>(hpw_s, tid, xs)       + hpb_f[tid];
    const float cv = dot1w<512>(cpw_s, tid, xs + 512) + cpb_f[tid];
    h0c0[(size_t)b * H_ + tid]              = tanhfast(hv);
    h0c0[(size_t)BH + (size_t)b * H_ + tid] = tanhfast(cv);
  }
}

// Decoder: 64 blocks x 1024 threads; per step all phases parallel over 16 waves.
__global__ __launch_bounds__(1024, 1) void dec_kernel(
    const int* __restrict__ src, const int* __restrict__ tgt, const float* __restrict__ emb_f,
    const unsigned short* __restrict__ d0_s, const unsigned short* __restrict__ d1_s,
    const unsigned short* __restrict__ wdec_s,
    const float* __restrict__ d0b, const float* __restrict__ d1b,
    const float* __restrict__ attv_f,
    const float* __restrict__ enc_out, const float* __restrict__ epT,
    const float* __restrict__ h0c0,
    float* __restrict__ dec_h)
{
  const int b = blockIdx.x, tid = threadIdx.x;
  __shared__ __align__(16) float xcat[1024];  // [xt | ctx(512) | hl0]
  __shared__ __align__(16) float hcat[512];   // [hl0 | hl1]
  __shared__ __align__(16) float gates[1024]; // gate rows; reused as ctx partials
  __shared__ __align__(16) float part[1024];  // q / score partials
  __shared__ __align__(16) float qs[256];
  __shared__ __align__(16) float sc[256];
  __shared__ __align__(16) float vv[256];
  __shared__ __align__(16) float mb[256];
  __shared__ float red[8];

  float cl0 = 0.0f, cl1 = 0.0f;
  const float bias0 = d0b[tid], bias1 = d1b[tid];
  if (tid < 256) {
    const float h0v = h0c0[(size_t)b * H_ + tid];
    const float c0v = h0c0[(size_t)B_ * H_ + (size_t)b * H_ + tid];
    cl0 = c0v; cl1 = c0v;
    xcat[768 + tid] = h0v;
    hcat[tid]       = h0v;
    hcat[256 + tid] = h0v;
    vv[tid] = attv_f[tid];
    mb[tid] = (src[(size_t)b * S_ + tid] == 0) ? -1e30f : 0.0f;
  }
  __syncthreads();

  const float* eo = enc_out + (size_t)b * S_ * 512;
  const float* ep = epT + (size_t)b * 65536;
  const int wid = tid >> 6;

  for (int t = 0; t < T_; ++t) {
    // ---- phase 1: q = hl1 @ Wdec.T, split K into 4 chunks; also prefetch xt embed
    {
      const int row = tid & 255, kq = tid >> 8;
      const uint4* p = (const uint4*)wdec_s + ((size_t)(row >> 6) * 32 + kq * 8) * 64 + (row & 63);
      const float* xq = hcat + 256 + kq * 64;
      float a = 0.0f;
      #pragma unroll
      for (int i = 0; i < 8; ++i) {
        const uint4 q = p[(size_t)i * 64];
        const float4 x0 = *(const float4*)(xq + i * 8);
        const float4 x1 = *(const float4*)(xq + i * 8 + 4);
        a += blo(q.x)*x0.x + bhi(q.x)*x0.y + blo(q.y)*x0.z + bhi(q.y)*x0.w
           + blo(q.z)*x1.x + bhi(q.z)*x1.y + blo(q.w)*x1.z + bhi(q.w)*x1.w;
      }
      part[kq * 256 + row] = a;
    }
    __syncthreads();
    if (tid < 256) {
      qs[tid] = part[tid] + part[256 + tid] + part[512 + tid] + part[768 + tid];
    } else if (tid < 512) {
      const int j = tid - 256;
      const int tok = tgt[(size_t)b * 257 + t];
      xcat[j] = emb_f[(size_t)tok * 256 + j];
    }
    __syncthreads();
    // ---- phase 2: scores, split jj into 4 chunks of 64
    {
      const int s = tid & 255, qq = tid >> 8;
      const float* epq = ep + (size_t)(qq * 64) * 256 + s;
      const float* vq = vv + qq * 64;
      const float* qq_ = qs + qq * 64;
      float a = 0.0f;
      #pragma unroll 4
      for (int i = 0; i < 64; ++i)
        a += vq[i] * tanhfast(epq[(size_t)i * 256] + qq_[i]);
      part[qq * 256 + s] = a;
    }
    __syncthreads();
    float e = 0.0f, pexp = 0.0f;
    if (tid < 256) {
      e = part[tid] + part[256 + tid] + part[512 + tid] + part[768 + tid] + mb[tid];
      float m = wredmax(e);
      if ((tid & 63) == 0) red[wid] = m;
    }
    __syncthreads();
    if (tid < 256) {
      const float m = fmaxf(fmaxf(red[0], red[1]), fmaxf(red[2], red[3]));
      pexp = __expf(e - m);
      float sm = wredsum(pexp);
      if ((tid & 63) == 0) red[4 + wid] = sm;
    }
    __syncthreads();
    if (tid < 256) {
      const float sm = (red[4] + red[5]) + (red[6] + red[7]);
      sc[tid] = pexp / sm;
    }
    __syncthreads();
    // ---- phase 3: ctx (512 dims), split s into 2 halves of 128
    {
      const int d = tid & 511, hh = tid >> 9;
      const float* eop = eo + (size_t)(hh * 128) * 512 + d;
      const float* scp = sc + hh * 128;
      float a = 0.0f;
      #pragma unroll 4
      for (int s2 = 0; s2 < 128; ++s2)
        a += scp[s2] * eop[(size_t)s2 * 512];
      gates[hh * 512 + d] = a;
    }
    __syncthreads();
    if (tid < 512) xcat[256 + tid] = gates[tid] + gates[512 + tid];
    __syncthreads();
    // ---- phase 4: cell0 gates over [xt|ctx|hl0] K=1024
    gates[tid] = bias0 + dot1w<1024>(d0_s, tid, xcat);
    __syncthreads();
    if (tid < 256) {
      float hn0;
      cellupd(gates[tid], gates[tid + 256], gates[tid + 512], gates[tid + 768], cl0, hn0);
      xcat[768 + tid] = hn0;
      hcat[tid]       = hn0;
    }
    __syncthreads();
    // ---- phase 5: cell1 gates over [hl0|hl1] K=512
    gates[tid] = bias1 + dot1w<512>(d1_s, tid, hcat);
    __syncthreads();
    if (tid < 256) {
      float hn1;
      cellupd(gates[tid], gates[tid + 256], gates[tid + 512], gates[tid + 768], cl1, hn1);
      hcat[256 + tid] = hn1;
      dec_h[((size_t)b * T_ + t) * H_ + tid] = hn1;
    }
    __syncthreads();
  }
}

// Final logits: out[row][v] = dec_h[row] . emb[v]  (1024 blocks x 16 rows), bf16 emb
__global__ __launch_bounds__(256) void out_kernel(
    const float* __restrict__ dec_h, const unsigned short* __restrict__ emb_s,
    void* __restrict__ out, const int* __restrict__ flagp)
{
  __shared__ __align__(16) float hs[16 * 256];
  const int blk = blockIdx.x, tid = threadIdx.x;
  const int isf32 = *flagp;
  const float* srcp = dec_h + (size_t)blk * (16 * 256);
  for (int i = tid; i < 16 * 256; i += 256) hs[i] = srcp[i];
  __syncthreads();
  #pragma unroll
  for (int vi = 0; vi < 4; ++vi) {
    const int v = tid + vi * 256;
    if (v < V_) {
      const uint4* p = (const uint4*)emb_s + (size_t)(v >> 6) * 32 * 64 + (v & 63); // KC=32
      float acc[16];
      #pragma unroll
      for (int r = 0; r < 16; ++r) acc[r] = 0.0f;
      for (int kc = 0; kc < 32; ++kc) {
        const uint4 q = p[(size_t)kc * 64];
        const float w0=blo(q.x), w1=bhi(q.x), w2=blo(q.y), w3=bhi(q.y),
                    w4=blo(q.z), w5=bhi(q.z), w6=blo(q.w), w7=bhi(q.w);
        #pragma unroll
        for (int r = 0; r < 16; ++r) {
          const float4 x0 = *(const float4*)(hs + r * 256 + kc * 8);
          const float4 x1 = *(const float4*)(hs + r * 256 + kc * 8 + 4);
          acc[r] += w0*x0.x + w1*x0.y + w2*x0.z + w3*x0.w + w4*x1.x + w5*x1.y + w6*x1.z + w7*x1.w;
        }
      }
      const size_t rowbase = (size_t)blk * 16;
      if (isf32) {
        float* o = (float*)out;
        #pragma unroll
        for (int r = 0; r < 16; ++r) o[(rowbase + r) * V_ + v] = acc[r];
      } else {
        __hip_bfloat16* o = (__hip_bfloat16*)out;
        #pragma unroll
        for (int r = 0; r < 16; ++r) o[(rowbase + r) * V_ + v] = __float2bfloat16(acc[r]);
      }
    }
  }
}

extern "C" void kernel_launch(void* const* d_in, const int* in_sizes, int n_in,
                              void* d_out, int out_size, void* d_ws, size_t ws_size,
                              hipStream_t stream)
{
  (void)in_sizes; (void)n_in; (void)out_size; (void)ws_size;
  const int* src = (const int*)d_in[0];
  const int* tgt = (const int*)d_in[1];

  // -------- workspace: flag | f32 activations | f32 biases | bf16 swizzled weights (~79 MB)
  char* base = (char*)d_ws;
  int* flag = (int*)base;
  float* ws = (float*)(base + 256);
  size_t off = 0;
  float* f0      = ws + off; off += (size_t)B_ * S_ * H_;
  float* b0      = ws + off; off += (size_t)B_ * S_ * H_;
  float* enc_out = ws + off; off += (size_t)B_ * S_ * 2 * H_;
  float* hcbuf   = ws + off; off += 4 * (size_t)B_ * H_;
  float* h0c0    = ws + off; off += 2 * (size_t)B_ * H_;
  float* emb_f   = ws + off; off += (size_t)V_ * D_;
  float* e0f_b   = ws + off; off += 1024;
  float* e0b_b   = ws + off; off += 1024;
  float* e1f_b   = ws + off; off += 1024;
  float* e1b_b   = ws + off; off += 1024;
  float* d0_b    = ws + off; off += 1024;
  float* d1_b    = ws + off; off += 1024;
  float* hpb_f   = ws + off; off += 256;
  float* cpb_f   = ws + off; off += 256;
  float* attv_f  = ws + off; off += 256;
  unsigned short* us = (unsigned short*)(ws + off);
  size_t uo = 0;
  unsigned short* e0f_s  = us + uo; uo += (size_t)1024 * 512;
  unsigned short* e0b_s  = us + uo; uo += (size_t)1024 * 512;
  unsigned short* e1f_s  = us + uo; uo += (size_t)1024 * 768;
  unsigned short* e1b_s  = us + uo; uo += (size_t)1024 * 768;
  unsigned short* d0_s   = us + uo; uo += (size_t)1024 * 1024;
  unsigned short* d1_s   = us + uo; uo += (size_t)1024 * 512;
  unsigned short* wdec_s = us + uo; uo += (size_t)256 * 256;
  unsigned short* wenc_s = us + uo; uo += (size_t)256 * 512;
  unsigned short* hpw_s  = us + uo; uo += (size_t)256 * 512;
  unsigned short* cpw_s  = us + uo; uo += (size_t)256 * 512;
  unsigned short* emb_s  = us + uo; uo += (size_t)1024 * 256;
  float* dec_h = f0;   // f0 dead after enc1
  float* epT   = b0;   // b0 dead after enc1

  hipLaunchKernelGGL(probe_kernel, dim3(1), dim3(64), 0, stream,
                     (const unsigned short*)d_in[3], flag);

  auto swz = [&](int idx, unsigned short* dst, int R, int Ks, int Kt, int c0){
    const int n = R * Ks;
    hipLaunchKernelGGL(swzb_kernel, dim3((n + 255) / 256), dim3(256), 0, stream,
                       d_in[idx], dst, R, Ks, Kt, c0, flag);
  };
  auto bias2 = [&](int ia, int ib, float* dst, int n){
    hipLaunchKernelGGL(bias_kernel, dim3((n + 255) / 256), dim3(256), 0, stream,
                       d_in[ia], d_in[ib], dst, n, flag);
  };

  hipLaunchKernelGGL(conv_kernel, dim3((V_ * D_ + 255) / 256), dim3(256), 0, stream,
                     d_in[2], emb_f, V_ * D_, flag);
  hipLaunchKernelGGL(conv_kernel, dim3(1), dim3(256), 0, stream, d_in[28], hpb_f, 256, flag);
  hipLaunchKernelGGL(conv_kernel, dim3(1), dim3(256), 0, stream, d_in[30], cpb_f, 256, flag);
  hipLaunchKernelGGL(conv_kernel, dim3(1), dim3(256), 0, stream, d_in[33], attv_f, 256, flag);
  bias2(5, 6, e0f_b, 1024);   bias2(9, 10, e0b_b, 1024);
  bias2(13, 14, e1f_b, 1024); bias2(17, 18, e1b_b, 1024);
  bias2(21, 22, d0_b, 1024);  bias2(25, 26, d1_b, 1024);
  swz(3,  e0f_s, 1024, 256, 512, 0);   swz(4,  e0f_s, 1024, 256, 512, 256);
  swz(7,  e0b_s, 1024, 256, 512, 0);   swz(8,  e0b_s, 1024, 256, 512, 256);
  swz(11, e1f_s, 1024, 512, 768, 0);   swz(12, e1f_s, 1024, 256, 768, 512);
  swz(15, e1b_s, 1024, 512, 768, 0);   swz(16, e1b_s, 1024, 256, 768, 512);
  swz(19, d0_s, 1024, 768, 1024, 0);   swz(20, d0_s, 1024, 256, 1024, 768);
  swz(23, d1_s, 1024, 256, 512, 0);    swz(24, d1_s, 1024, 256, 512, 256);
  swz(32, wdec_s, 256, 256, 256, 0);
  swz(31, wenc_s, 256, 512, 512, 0);
  swz(27, hpw_s, 256, 512, 512, 0);
  swz(29, cpw_s, 256, 512, 512, 0);
  swz(2,  emb_s, 1000, 256, 256, 0);

  hipLaunchKernelGGL(enc0_kernel, dim3(128), dim3(1024), 0, stream,
                     src, emb_f, e0f_s, e0b_s, e0f_b, e0b_b, f0, b0);
  hipLaunchKernelGGL(enc1_kernel, dim3(128), dim3(1024), 0, stream,
                     f0, b0, e1f_s, e1b_s, e1f_b, e1b_b, enc_out, hcbuf);
  hipLaunchKernelGGL(proj_kernel, dim3(1088), dim3(256), 0, stream,
                     enc_out, hcbuf, wenc_s, hpw_s, cpw_s, hpb_f, cpb_f, epT, h0c0);
  hipLaunchKernelGGL(dec_kernel, dim3(64), dim3(1024), 0, stream,
                     src, tgt, emb_f, d0_s, d1_s, wdec_s, d0_b, d1_b, attv_f,
                     enc_out, epT, h0c0, dec_h);
  hipLaunchKernelGGL(out_kernel, dim3(1024), dim3(256), 0, stream,
                     dec_h, emb_s, d_out, flag);
}

// Round 4
// 28380.356 us; speedup vs baseline: 1.6546x; 1.0152x over previous
//
#include <hip/hip_runtime.h>
#include <hip/hip_bf16.h>
#include <stdint.h>

#define B_ 64
#define S_ 256
#define T_ 256
#define D_ 256
#define H_ 256
#define V_ 1000

__device__ __forceinline__ float blo(unsigned u){ return __uint_as_float(u << 16); }
__device__ __forceinline__ float bhi(unsigned u){ return __uint_as_float(u & 0xffff0000u); }
__device__ __forceinline__ float sigm(float x){ return 1.0f / (1.0f + __expf(-x)); }
__device__ __forceinline__ float tanhfast(float x){ float e = __expf(2.0f * x); return 1.0f - 2.0f / (e + 1.0f); }

__device__ __forceinline__ void cellupd(float a0, float a1, float a2, float a3, float& c, float& h){
  float cn = sigm(a1) * c + sigm(a0) * tanhfast(a2);
  c = cn;
  h = sigm(a3) * tanhfast(cn);
}

__device__ __forceinline__ float wredmax(float v){
  #pragma unroll
  for (int o = 32; o > 0; o >>= 1) v = fmaxf(v, __shfl_xor(v, o));
  return v;
}
__device__ __forceinline__ float wredsum(float v){
  #pragma unroll
  for (int o = 32; o > 0; o >>= 1) v += __shfl_xor(v, o);
  return v;
}

// agent-scope data movement for cross-block (cross-XCD) sharing inside dec_kernel
__device__ __forceinline__ void ast(float* p, float v){
  __hip_atomic_store(p, v, __ATOMIC_RELAXED, __HIP_MEMORY_SCOPE_AGENT);
}
__device__ __forceinline__ float ald(const float* p){
  return __hip_atomic_load(p, __ATOMIC_RELAXED, __HIP_MEMORY_SCOPE_AGENT);
}

// 4-way sense-reversing group barrier (cnt,gen per group, device scope)
__device__ __forceinline__ void groupbar(int* cnt, int* gen){
  __syncthreads();
  if (threadIdx.x == 0) {
    int g = __hip_atomic_load(gen, __ATOMIC_RELAXED, __HIP_MEMORY_SCOPE_AGENT);
    int old = __hip_atomic_fetch_add(cnt, 1, __ATOMIC_ACQ_REL, __HIP_MEMORY_SCOPE_AGENT);
    if (old == 3) {
      __hip_atomic_store(cnt, 0, __ATOMIC_RELAXED, __HIP_MEMORY_SCOPE_AGENT);
      __hip_atomic_fetch_add(gen, 1, __ATOMIC_RELEASE, __HIP_MEMORY_SCOPE_AGENT);
    } else {
      int spins = 0;
      while (__hip_atomic_load(gen, __ATOMIC_ACQUIRE, __HIP_MEMORY_SCOPE_AGENT) == g) {
        __builtin_amdgcn_s_sleep(2);
        if (++spins > (1 << 23)) break;  // fail loudly (bad absmax), never hang
      }
    }
  }
  __syncthreads();
}

// ---------------- dtype probe ----------------
__global__ void probe_kernel(const unsigned short* __restrict__ w, int* __restrict__ flag)
{
  int cnt = 0;
  for (int i = threadIdx.x; i < 4096; i += 64) {
    unsigned e = (w[i] >> 7) & 0xFFu;
    if (e >= 0xC0u) cnt++;
  }
  #pragma unroll
  for (int o = 32; o > 0; o >>= 1) cnt += __shfl_xor(cnt, o);
  if (threadIdx.x == 0) *flag = (cnt > 32) ? 1 : 0;
}

__device__ __forceinline__ float load_any(const void* src, int i, int isf32){
  return isf32 ? ((const float*)src)[i]
               : __uint_as_float(((unsigned)((const unsigned short*)src)[i]) << 16);
}

__global__ void conv_kernel(const void* __restrict__ src, float* __restrict__ dst, int n,
                            const int* __restrict__ flagp)
{
  int i = blockIdx.x * 256 + threadIdx.x;
  if (i >= n) return;
  dst[i] = load_any(src, i, *flagp);
}

__global__ void bias_kernel(const void* __restrict__ a, const void* __restrict__ bsrc,
                            float* __restrict__ dst, int n, const int* __restrict__ flagp)
{
  int i = blockIdx.x * 256 + threadIdx.x;
  if (i >= n) return;
  int f = *flagp;
  dst[i] = load_any(a, i, f) + load_any(bsrc, i, f);
}

__global__ void barinit_kernel(int* __restrict__ bars)
{
  bars[blockIdx.x * 256 + threadIdx.x] = 0;
}

// Swizzled bf16 weight layout for an (R x K) matrix:
//   swz[ (((r>>6)*(K>>3) + (k>>3))*64 + (r&63))*8 + (k&7) ] = bf16(W[r][k])
__global__ void swzb_kernel(const void* __restrict__ src, unsigned short* __restrict__ dst,
                            int R, int Ks, int Kt, int c0, const int* __restrict__ flagp)
{
  int i = blockIdx.x * 256 + threadIdx.x;
  if (i >= R * Ks) return;
  int r = i / Ks;
  int k = i - r * Ks;
  int kk = k + c0;
  float v = load_any(src, i, *flagp);
  __hip_bfloat16 bv = __float2bfloat16(v);
  dst[(((size_t)(r >> 6) * (size_t)(Kt >> 3) + (size_t)(kk >> 3)) * 64 + (r & 63)) * 8 + (kk & 7)] =
      *(unsigned short*)&bv;
}

// one full row r of an (R x K) swizzled bf16 matrix, x in LDS
template<int K>
__device__ __forceinline__ float dot1w(const unsigned short* __restrict__ w, int r,
                                       const float* __restrict__ xs)
{
  constexpr int KC = K >> 3;
  const uint4* __restrict__ p = (const uint4*)w + (size_t)(r >> 6) * KC * 64 + (r & 63);
  float a = 0.0f;
  #pragma unroll 4
  for (int kc = 0; kc < KC; ++kc) {
    const uint4 q = p[(size_t)kc * 64];
    const float4 x0 = *(const float4*)(xs + kc * 8);
    const float4 x1 = *(const float4*)(xs + kc * 8 + 4);
    a += blo(q.x)*x0.x + bhi(q.x)*x0.y + blo(q.y)*x0.z + bhi(q.y)*x0.w
       + blo(q.z)*x1.x + bhi(q.z)*x1.y + blo(q.w)*x1.z + bhi(q.w)*x1.w;
  }
  return a;
}

// Encoder layer 0 (unchanged from round 3)
__global__ __launch_bounds__(1024, 1) void enc0_kernel(
    const int* __restrict__ src, const float* __restrict__ emb_f,
    const unsigned short* __restrict__ wF, const unsigned short* __restrict__ wB,
    const float* __restrict__ bF, const float* __restrict__ bB,
    float* __restrict__ f0, float* __restrict__ b0)
{
  const int blk = blockIdx.x, dir = blk >> 6, b = blk & 63, tid = threadIdx.x;
  const unsigned short* w = dir ? wB : wF;
  const float* bi = dir ? bB : bF;
  float* outp = dir ? b0 : f0;
  __shared__ __align__(16) float xs[512];
  __shared__ __align__(16) float gates[1024];
  const float bias = bi[tid];
  float c = 0.0f, h = 0.0f;
  if (tid < 256) xs[256 + tid] = 0.0f;
  const size_t bS = (size_t)b * S_;
  for (int t = 0; t < S_; ++t) {
    const int tp = dir ? (S_ - 1 - t) : t;
    const int tok = src[bS + tp];
    if (tid < 256) xs[tid] = emb_f[(size_t)tok * D_ + tid];
    __syncthreads();
    gates[tid] = bias + dot1w<512>(w, tid, xs);
    __syncthreads();
    if (tid < 256) {
      cellupd(gates[tid], gates[tid + 256], gates[tid + 512], gates[tid + 768], c, h);
      xs[256 + tid] = h;
      outp[(bS + tp) * H_ + tid] = h;
    }
    __syncthreads();
  }
}

// Encoder layer 1 (unchanged from round 3)
__global__ __launch_bounds__(1024, 1) void enc1_kernel(
    const float* __restrict__ f0, const float* __restrict__ b0,
    const unsigned short* __restrict__ wF, const unsigned short* __restrict__ wB,
    const float* __restrict__ bF, const float* __restrict__ bB,
    float* __restrict__ enc_out, float* __restrict__ hcbuf)
{
  const int blk = blockIdx.x, dir = blk >> 6, b = blk & 63, tid = threadIdx.x;
  const unsigned short* w = dir ? wB : wF;
  const float* bi = dir ? bB : bF;
  __shared__ __align__(16) float xs[768];
  __shared__ __align__(16) float gates[1024];
  const float bias = bi[tid];
  float c = 0.0f, h = 0.0f;
  if (tid < 256) xs[512 + tid] = 0.0f;
  const size_t bS = (size_t)b * S_;
  for (int t = 0; t < S_; ++t) {
    const int tp = dir ? (S_ - 1 - t) : t;
    const size_t row = (bS + tp) * (size_t)H_;
    if (tid < 512) {
      const int jj = tid & 255;
      xs[tid] = (tid < 256) ? f0[row + jj] : b0[row + jj];
    }
    __syncthreads();
    gates[tid] = bias + dot1w<768>(w, tid, xs);
    __syncthreads();
    if (tid < 256) {
      cellupd(gates[tid], gates[tid + 256], gates[tid + 512], gates[tid + 768], c, h);
      xs[512 + tid] = h;
      enc_out[(bS + tp) * 512 + dir * 256 + tid] = h;
    }
    __syncthreads();
  }
  if (tid < 256) {
    const int BH = B_ * H_;
    float* hout = hcbuf + (dir ? 2 * BH : 0);
    hout[(size_t)b * H_ + tid]      = h;
    hout[BH + (size_t)b * H_ + tid] = c;
  }
}

// proj (unchanged from round 3)
__global__ __launch_bounds__(256) void proj_kernel(
    const float* __restrict__ enc_out, const float* __restrict__ hcbuf,
    const unsigned short* __restrict__ wenc_s,
    const unsigned short* __restrict__ hpw_s, const unsigned short* __restrict__ cpw_s,
    const float* __restrict__ hpb_f, const float* __restrict__ cpb_f,
    float* __restrict__ epT, float* __restrict__ h0c0)
{
  __shared__ __align__(16) float xs[16 * 512];
  const int blk = blockIdx.x, tid = threadIdx.x;
  if (blk < 1024) {
    const int b = blk >> 4, s0 = (blk & 15) * 16;
    const float* srcp = enc_out + ((size_t)b * S_ + s0) * 512;
    for (int i = tid; i < 16 * 512; i += 256) xs[i] = srcp[i];
    __syncthreads();
    float acc[16];
    #pragma unroll
    for (int r = 0; r < 16; ++r) acc[r] = 0.0f;
    const uint4* p = (const uint4*)wenc_s + (size_t)(tid >> 6) * 64 * 64 + (tid & 63);
    for (int kc = 0; kc < 64; ++kc) {
      const uint4 q = p[(size_t)kc * 64];
      const float w0=blo(q.x), w1=bhi(q.x), w2=blo(q.y), w3=bhi(q.y),
                  w4=blo(q.z), w5=bhi(q.z), w6=blo(q.w), w7=bhi(q.w);
      #pragma unroll
      for (int r = 0; r < 16; ++r) {
        const float4 x0 = *(const float4*)(xs + r * 512 + kc * 8);
        const float4 x1 = *(const float4*)(xs + r * 512 + kc * 8 + 4);
        acc[r] += w0*x0.x + w1*x0.y + w2*x0.z + w3*x0.w + w4*x1.x + w5*x1.y + w6*x1.z + w7*x1.w;
      }
    }
    float* dst = epT + ((size_t)b * S_ + (size_t)tid) * 256 + s0;
    #pragma unroll
    for (int r = 0; r < 16; ++r) dst[r] = acc[r];
  } else {
    const int b = blk - 1024;
    const int BH = B_ * H_;
    xs[tid]        = hcbuf[(size_t)b * H_ + tid];
    xs[256 + tid]  = hcbuf[2 * BH + (size_t)b * H_ + tid];
    xs[512 + tid]  = hcbuf[BH + (size_t)b * H_ + tid];
    xs[768 + tid]  = hcbuf[3 * BH + (size_t)b * H_ + tid];
    __syncthreads();
    const float hv = dot1w<512>(hpw_s, tid, xs)       + hpb_f[tid];
    const float cv = dot1w<512>(cpw_s, tid, xs + 512) + cpb_f[tid];
    h0c0[(size_t)b * H_ + tid]              = tanhfast(hv);
    h0c0[(size_t)BH + (size_t)b * H_ + tid] = tanhfast(cv);
  }
}

// ---------------- decoder: 256 blocks = 4 per batch (p = j-slice of 64) ----------------
// share[b] layout (f32): [0..2047] xcat dbuf (2x1024: xt|ctx|hl0)
//                        [2048..3071] hcat dbuf (2x512: hl0|hl1)
//                        [3072..4095] part (4x256 score partials)
#define SH_XC  0
#define SH_HC  2048
#define SH_PT  3072
#define SH_B   4096

__global__ __launch_bounds__(512, 1) void dec_kernel(
    const int* __restrict__ src, const int* __restrict__ tgt, const float* __restrict__ emb_f,
    const unsigned short* __restrict__ d0_s, const unsigned short* __restrict__ d1_s,
    const unsigned short* __restrict__ wdec_s,
    const float* __restrict__ d0b, const float* __restrict__ d1b,
    const float* __restrict__ attv_f,
    const float* __restrict__ enc_out, const float* __restrict__ epT,
    const float* __restrict__ h0c0,
    float* __restrict__ share, int* __restrict__ bars,
    float* __restrict__ dec_h)
{
  const int blk = blockIdx.x, b = blk >> 2, p = blk & 3, tid = threadIdx.x;
  const int lane = tid & 63;

  __shared__ __align__(16) float xsh[1024];
  __shared__ __align__(16) float work[512];
  __shared__ __align__(16) float sc_s[256];
  __shared__ __align__(16) float gcomb[256];
  __shared__ __align__(16) float qv[64];
  __shared__ __align__(16) float vv_s[256];
  __shared__ __align__(16) float mb_s[256];
  __shared__ __align__(16) float bias0_s[256];
  __shared__ __align__(16) float bias1_s[256];
  __shared__ float red_s[8];

  float* sh = share + (size_t)b * SH_B;
  int* cnt = bars + b * 16;
  int* gen = bars + b * 16 + 1;

  // ---- init ----
  if (tid < 256) {
    vv_s[tid] = attv_f[tid];
    mb_s[tid] = (src[(size_t)b * S_ + tid] == 0) ? -1e30f : 0.0f;
    const int gg = tid >> 6, l = tid & 63;
    bias0_s[tid] = d0b[gg * 256 + p * 64 + l];
    bias1_s[tid] = d1b[gg * 256 + p * 64 + l];
  }
  float cl0 = 0.0f, cl1 = 0.0f;
  if (tid < 64) {
    const int j = p * 64 + tid;
    const float h0v = h0c0[(size_t)b * H_ + j];
    const float c0v = h0c0[(size_t)B_ * H_ + (size_t)b * H_ + j];
    cl0 = c0v; cl1 = c0v;
    ast(&sh[SH_XC + 768 + j], h0v);        // xcat[par=0] hl0 slot
    ast(&sh[SH_HC + 256 + j], h0v);        // hcat[par=0] hl1 slot
  }
  groupbar(cnt, gen);

  const float* eo = enc_out + (size_t)b * S_ * 512;
  const float* ep = epT + (size_t)b * 65536;

  int pt = 0;
  for (int t = 0; t < T_; ++t) {
    float* xc_cur = sh + SH_XC + pt * 1024;
    float* xc_nxt = sh + SH_XC + (1 - pt) * 1024;
    float* hc_cur = sh + SH_HC + pt * 512;
    float* hc_nxt = sh + SH_HC + (1 - pt) * 512;
    float* part = sh + SH_PT;

    // ---- phase A: q over jj-slice, score partials for all s; stage xt slice
    if (tid < 256) xsh[tid] = ald(&hc_cur[256 + tid]);   // hl1(t-1)
    __syncthreads();
    {
      const int prt = tid >> 6;   // 0..7, K-split of 32 each
      const uint4* wq = (const uint4*)wdec_s + ((size_t)p * 32 + prt * 4) * 64 + lane;
      float a = 0.0f;
      #pragma unroll
      for (int i = 0; i < 4; ++i) {
        const uint4 q = wq[(size_t)i * 64];
        const float* xq = xsh + (prt * 4 + i) * 8;
        const float4 x0 = *(const float4*)(xq);
        const float4 x1 = *(const float4*)(xq + 4);
        a += blo(q.x)*x0.x + bhi(q.x)*x0.y + blo(q.y)*x0.z + bhi(q.y)*x0.w
           + blo(q.z)*x1.x + bhi(q.z)*x1.y + blo(q.w)*x1.z + bhi(q.w)*x1.w;
      }
      work[tid] = a;
    }
    __syncthreads();
    if (tid < 64) {
      float a = 0.0f;
      #pragma unroll
      for (int i = 0; i < 8; ++i) a += work[i * 64 + tid];
      qv[tid] = a;   // q[jj-slice]
    } else if (tid < 128) {
      const int k = tid - 64;
      const int tok = tgt[(size_t)b * 257 + t];
      ast(&xc_cur[p * 64 + k], emb_f[(size_t)tok * 256 + p * 64 + k]);
    }
    __syncthreads();
    {
      const int jh = tid >> 8, s = tid & 255;   // jh in {0,1}: 32 jj each
      const float* epp = ep + (size_t)(p * 64 + jh * 32) * 256 + s;
      float a = 0.0f;
      #pragma unroll 4
      for (int i = 0; i < 32; ++i)
        a += vv_s[p * 64 + jh * 32 + i] * tanhfast(epp[(size_t)i * 256] + qv[jh * 32 + i]);
      work[jh * 256 + s] = a;
    }
    __syncthreads();
    if (tid < 256) ast(&part[p * 256 + tid], work[tid] + work[256 + tid]);
    groupbar(cnt, gen);

    // ---- phase B: redundant softmax from 4 partials; ctx d-slice
    float e = 0.0f, pexp = 0.0f;
    if (tid < 256) {
      e = ald(&part[tid]) + ald(&part[256 + tid]) + ald(&part[512 + tid]) + ald(&part[768 + tid])
        + mb_s[tid];
      float m = wredmax(e);
      if ((tid & 63) == 0) red_s[tid >> 6] = m;
    }
    __syncthreads();
    if (tid < 256) {
      const float m = fmaxf(fmaxf(red_s[0], red_s[1]), fmaxf(red_s[2], red_s[3]));
      pexp = __expf(e - m);
      float sm = wredsum(pexp);
      if ((tid & 63) == 0) red_s[4 + (tid >> 6)] = sm;
    }
    __syncthreads();
    if (tid < 256) {
      const float sm = (red_s[4] + red_s[5]) + (red_s[6] + red_s[7]);
      sc_s[tid] = pexp / sm;
    }
    __syncthreads();
    {
      const int schunk = tid >> 7, dd = tid & 127;   // 4 chunks of 64 s
      const float* eop = eo + (size_t)(schunk * 64) * 512 + p * 128 + dd;
      const float* scp = sc_s + schunk * 64;
      float a = 0.0f;
      #pragma unroll 4
      for (int i = 0; i < 64; ++i)
        a += scp[i] * eop[(size_t)i * 512];
      work[schunk * 128 + dd] = a;
    }
    __syncthreads();
    if (tid < 128)
      ast(&xc_cur[256 + p * 128 + tid],
          work[tid] + work[128 + tid] + work[256 + tid] + work[384 + tid]);
    groupbar(cnt, gen);

    // ---- phase C0: cell0 gates, 256 rows (4 gates x 64 j), K=1024
    xsh[tid] = ald(&xc_cur[tid]);
    xsh[tid + 512] = ald(&xc_cur[tid + 512]);
    __syncthreads();
    {
      const int g = tid >> 7, half = (tid >> 6) & 1;
      const int rg = g * 4 + p;   // 64-row group index
      const uint4* w = (const uint4*)d0_s + ((size_t)rg * 128 + half * 64) * 64 + lane;
      const float* xl = xsh + half * 512;
      float a = 0.0f;
      #pragma unroll 4
      for (int kc = 0; kc < 64; ++kc) {
        const uint4 q = w[(size_t)kc * 64];
        const float4 x0 = *(const float4*)(xl + kc * 8);
        const float4 x1 = *(const float4*)(xl + kc * 8 + 4);
        a += blo(q.x)*x0.x + bhi(q.x)*x0.y + blo(q.y)*x0.z + bhi(q.y)*x0.w
           + blo(q.z)*x1.x + bhi(q.z)*x1.y + blo(q.w)*x1.z + bhi(q.w)*x1.w;
      }
      work[tid] = a;
    }
    __syncthreads();
    if (tid < 256) {
      const int gg = tid >> 6, l = tid & 63;
      gcomb[gg * 64 + l] = work[gg * 128 + l] + work[gg * 128 + 64 + l] + bias0_s[tid];
    }
    __syncthreads();
    if (tid < 64) {
      float hn0;
      cellupd(gcomb[tid], gcomb[64 + tid], gcomb[128 + tid], gcomb[192 + tid], cl0, hn0);
      ast(&hc_cur[p * 64 + tid], hn0);           // for C1 this step
      ast(&xc_nxt[768 + p * 64 + tid], hn0);     // for C0 next step
    }
    groupbar(cnt, gen);

    // ---- phase C1: cell1 gates, 256 rows, K=512 over [hl0(t)|hl1(t-1)]
    if (tid < 512) xsh[tid] = ald(&hc_cur[tid]);
    __syncthreads();
    {
      const int g = tid >> 7, half = (tid >> 6) & 1;
      const int rg = g * 4 + p;
      const uint4* w = (const uint4*)d1_s + ((size_t)rg * 64 + half * 32) * 64 + lane;
      const float* xl = xsh + half * 256;
      float a = 0.0f;
      #pragma unroll 4
      for (int kc = 0; kc < 32; ++kc) {
        const uint4 q = w[(size_t)kc * 64];
        const float4 x0 = *(const float4*)(xl + kc * 8);
        const float4 x1 = *(const float4*)(xl + kc * 8 + 4);
        a += blo(q.x)*x0.x + bhi(q.x)*x0.y + blo(q.y)*x0.z + bhi(q.y)*x0.w
           + blo(q.z)*x1.x + bhi(q.z)*x1.y + blo(q.w)*x1.z + bhi(q.w)*x1.w;
      }
      work[tid] = a;
    }
    __syncthreads();
    if (tid < 256) {
      const int gg = tid >> 6, l = tid & 63;
      gcomb[gg * 64 + l] = work[gg * 128 + l] + work[gg * 128 + 64 + l] + bias1_s[tid];
    }
    __syncthreads();
    if (tid < 64) {
      float hn1;
      cellupd(gcomb[tid], gcomb[64 + tid], gcomb[128 + tid], gcomb[192 + tid], cl1, hn1);
      ast(&hc_nxt[256 + p * 64 + tid], hn1);     // hl1(t) for next step / A
      dec_h[((size_t)b * T_ + t) * H_ + p * 64 + tid] = hn1;
    }
    groupbar(cnt, gen);

    pt = 1 - pt;
  }
}

// out (unchanged from round 3)
__global__ __launch_bounds__(256) void out_kernel(
    const float* __restrict__ dec_h, const unsigned short* __restrict__ emb_s,
    void* __restrict__ out, const int* __restrict__ flagp)
{
  __shared__ __align__(16) float hs[16 * 256];
  const int blk = blockIdx.x, tid = threadIdx.x;
  const int isf32 = *flagp;
  const float* srcp = dec_h + (size_t)blk * (16 * 256);
  for (int i = tid; i < 16 * 256; i += 256) hs[i] = srcp[i];
  __syncthreads();
  #pragma unroll
  for (int vi = 0; vi < 4; ++vi) {
    const int v = tid + vi * 256;
    if (v < V_) {
      const uint4* p = (const uint4*)emb_s + (size_t)(v >> 6) * 32 * 64 + (v & 63);
      float acc[16];
      #pragma unroll
      for (int r = 0; r < 16; ++r) acc[r] = 0.0f;
      for (int kc = 0; kc < 32; ++kc) {
        const uint4 q = p[(size_t)kc * 64];
        const float w0=blo(q.x), w1=bhi(q.x), w2=blo(q.y), w3=bhi(q.y),
                    w4=blo(q.z), w5=bhi(q.z), w6=blo(q.w), w7=bhi(q.w);
        #pragma unroll
        for (int r = 0; r < 16; ++r) {
          const float4 x0 = *(const float4*)(hs + r * 256 + kc * 8);
          const float4 x1 = *(const float4*)(hs + r * 256 + kc * 8 + 4);
          acc[r] += w0*x0.x + w1*x0.y + w2*x0.z + w3*x0.w + w4*x1.x + w5*x1.y + w6*x1.z + w7*x1.w;
        }
      }
      const size_t rowbase = (size_t)blk * 16;
      if (isf32) {
        float* o = (float*)out;
        #pragma unroll
        for (int r = 0; r < 16; ++r) o[(rowbase + r) * V_ + v] = acc[r];
      } else {
        __hip_bfloat16* o = (__hip_bfloat16*)out;
        #pragma unroll
        for (int r = 0; r < 16; ++r) o[(rowbase + r) * V_ + v] = __float2bfloat16(acc[r]);
      }
    }
  }
}

extern "C" void kernel_launch(void* const* d_in, const int* in_sizes, int n_in,
                              void* d_out, int out_size, void* d_ws, size_t ws_size,
                              hipStream_t stream)
{
  (void)in_sizes; (void)n_in; (void)out_size; (void)ws_size;
  const int* src = (const int*)d_in[0];
  const int* tgt = (const int*)d_in[1];

  char* base = (char*)d_ws;
  int* flag = (int*)base;
  int* bars = (int*)(base + 256);          // 64 groups x 16 ints
  float* ws = (float*)(base + 256 + 64 * 16 * 4);
  size_t off = 0;
  float* f0      = ws + off; off += (size_t)B_ * S_ * H_;
  float* b0      = ws + off; off += (size_t)B_ * S_ * H_;
  float* enc_out = ws + off; off += (size_t)B_ * S_ * 2 * H_;
  float* hcbuf   = ws + off; off += 4 * (size_t)B_ * H_;
  float* h0c0    = ws + off; off += 2 * (size_t)B_ * H_;
  float* emb_f   = ws + off; off += (size_t)V_ * D_;
  float* share   = ws + off; off += (size_t)B_ * SH_B;
  float* e0f_b   = ws + off; off += 1024;
  float* e0b_b   = ws + off; off += 1024;
  float* e1f_b   = ws + off; off += 1024;
  float* e1b_b   = ws + off; off += 1024;
  float* d0_b    = ws + off; off += 1024;
  float* d1_b    = ws + off; off += 1024;
  float* hpb_f   = ws + off; off += 256;
  float* cpb_f   = ws + off; off += 256;
  float* attv_f  = ws + off; off += 256;
  unsigned short* us = (unsigned short*)(ws + off);
  size_t uo = 0;
  unsigned short* e0f_s  = us + uo; uo += (size_t)1024 * 512;
  unsigned short* e0b_s  = us + uo; uo += (size_t)1024 * 512;
  unsigned short* e1f_s  = us + uo; uo += (size_t)1024 * 768;
  unsigned short* e1b_s  = us + uo; uo += (size_t)1024 * 768;
  unsigned short* d0_s   = us + uo; uo += (size_t)1024 * 1024;
  unsigned short* d1_s   = us + uo; uo += (size_t)1024 * 512;
  unsigned short* wdec_s = us + uo; uo += (size_t)256 * 256;
  unsigned short* wenc_s = us + uo; uo += (size_t)256 * 512;
  unsigned short* hpw_s  = us + uo; uo += (size_t)256 * 512;
  unsigned short* cpw_s  = us + uo; uo += (size_t)256 * 512;
  unsigned short* emb_s  = us + uo; uo += (size_t)1024 * 256;
  float* dec_h = f0;
  float* epT   = b0;

  hipLaunchKernelGGL(probe_kernel, dim3(1), dim3(64), 0, stream,
                     (const unsigned short*)d_in[3], flag);
  hipLaunchKernelGGL(barinit_kernel, dim3(4), dim3(256), 0, stream, bars);

  auto swz = [&](int idx, unsigned short* dst, int R, int Ks, int Kt, int c0){
    const int n = R * Ks;
    hipLaunchKernelGGL(swzb_kernel, dim3((n + 255) / 256), dim3(256), 0, stream,
                       d_in[idx], dst, R, Ks, Kt, c0, flag);
  };
  auto bias2 = [&](int ia, int ib, float* dst, int n){
    hipLaunchKernelGGL(bias_kernel, dim3((n + 255) / 256), dim3(256), 0, stream,
                       d_in[ia], d_in[ib], dst, n, flag);
  };

  hipLaunchKernelGGL(conv_kernel, dim3((V_ * D_ + 255) / 256), dim3(256), 0, stream,
                     d_in[2], emb_f, V_ * D_, flag);
  hipLaunchKernelGGL(conv_kernel, dim3(1), dim3(256), 0, stream, d_in[28], hpb_f, 256, flag);
  hipLaunchKernelGGL(conv_kernel, dim3(1), dim3(256), 0, stream, d_in[30], cpb_f, 256, flag);
  hipLaunchKernelGGL(conv_kernel, dim3(1), dim3(256), 0, stream, d_in[33], attv_f, 256, flag);
  bias2(5, 6, e0f_b, 1024);   bias2(9, 10, e0b_b, 1024);
  bias2(13, 14, e1f_b, 1024); bias2(17, 18, e1b_b, 1024);
  bias2(21, 22, d0_b, 1024);  bias2(25, 26, d1_b, 1024);
  swz(3,  e0f_s, 1024, 256, 512, 0);   swz(4,  e0f_s, 1024, 256, 512, 256);
  swz(7,  e0b_s, 1024, 256, 512, 0);   swz(8,  e0b_s, 1024, 256, 512, 256);
  swz(11, e1f_s, 1024, 512, 768, 0);   swz(12, e1f_s, 1024, 256, 768, 512);
  swz(15, e1b_s, 1024, 512, 768, 0);   swz(16, e1b_s, 1024, 256, 768, 512);
  swz(19, d0_s, 1024, 768, 1024, 0);   swz(20, d0_s, 1024, 256, 1024, 768);
  swz(23, d1_s, 1024, 256, 512, 0);    swz(24, d1_s, 1024, 256, 512, 256);
  swz(32, wdec_s, 256, 256, 256, 0);
  swz(31, wenc_s, 256, 512, 512, 0);
  swz(27, hpw_s, 256, 512, 512, 0);
  swz(29, cpw_s, 256, 512, 512, 0);
  swz(2,  emb_s, 1000, 256, 256, 0);

  hipLaunchKernelGGL(enc0_kernel, dim3(128), dim3(1024), 0, stream,
                     src, emb_f, e0f_s, e0b_s, e0f_b, e0b_b, f0, b0);
  hipLaunchKernelGGL(enc1_kernel, dim3(128), dim3(1024), 0, stream,
                     f0, b0, e1f_s, e1b_s, e1f_b, e1b_b, enc_out, hcbuf);
  hipLaunchKernelGGL(proj_kernel, dim3(1088), dim3(256), 0, stream,
                     enc_out, hcbuf, wenc_s, hpw_s, cpw_s, hpb_f, cpb_f, epT, h0c0);
  hipLaunchKernelGGL(dec_kernel, dim3(256), dim3(512), 0, stream,
                     src, tgt, emb_f, d0_s, d1_s, wdec_s, d0_b, d1_b, attv_f,
                     enc_out, epT, h0c0, share, bars, dec_h);
  hipLaunchKernelGGL(out_kernel, dim3(1024), dim3(256), 0, stream,
                     dec_h, emb_s, d_out, flag);
}

// Round 5
// 22995.891 us; speedup vs baseline: 2.0420x; 1.2341x over previous
//
#include <hip/hip_runtime.h>
#include <hip/hip_bf16.h>
#include <stdint.h>

#define B_ 64
#define S_ 256
#define T_ 256
#define D_ 256
#define H_ 256
#define V_ 1000

__device__ __forceinline__ float blo(unsigned u){ return __uint_as_float(u << 16); }
__device__ __forceinline__ float bhi(unsigned u){ return __uint_as_float(u & 0xffff0000u); }
__device__ __forceinline__ float sigm(float x){ return 1.0f / (1.0f + __expf(-x)); }
__device__ __forceinline__ float tanhfast(float x){ float e = __expf(2.0f * x); return 1.0f - 2.0f / (e + 1.0f); }

__device__ __forceinline__ void cellupd(float a0, float a1, float a2, float a3, float& c, float& h){
  float cn = sigm(a1) * c + sigm(a0) * tanhfast(a2);
  c = cn;
  h = sigm(a3) * tanhfast(cn);
}

__device__ __forceinline__ float wredmax(float v){
  #pragma unroll
  for (int o = 32; o > 0; o >>= 1) v = fmaxf(v, __shfl_xor(v, o));
  return v;
}
__device__ __forceinline__ float wredsum(float v){
  #pragma unroll
  for (int o = 32; o > 0; o >>= 1) v += __shfl_xor(v, o);
  return v;
}

// ---------------- dtype probe ----------------
__global__ void probe_kernel(const unsigned short* __restrict__ w, int* __restrict__ flag)
{
  int cnt = 0;
  for (int i = threadIdx.x; i < 4096; i += 64) {
    unsigned e = (w[i] >> 7) & 0xFFu;
    if (e >= 0xC0u) cnt++;
  }
  #pragma unroll
  for (int o = 32; o > 0; o >>= 1) cnt += __shfl_xor(cnt, o);
  if (threadIdx.x == 0) *flag = (cnt > 32) ? 1 : 0;
}

__device__ __forceinline__ float load_any(const void* src, int i, int isf32){
  return isf32 ? ((const float*)src)[i]
               : __uint_as_float(((unsigned)((const unsigned short*)src)[i]) << 16);
}

__global__ void conv_kernel(const void* __restrict__ src, float* __restrict__ dst, int n,
                            const int* __restrict__ flagp)
{
  int i = blockIdx.x * 256 + threadIdx.x;
  if (i >= n) return;
  dst[i] = load_any(src, i, *flagp);
}

__global__ void bias_kernel(const void* __restrict__ a, const void* __restrict__ bsrc,
                            float* __restrict__ dst, int n, const int* __restrict__ flagp)
{
  int i = blockIdx.x * 256 + threadIdx.x;
  if (i >= n) return;
  int f = *flagp;
  dst[i] = load_any(a, i, f) + load_any(bsrc, i, f);
}

// Swizzled bf16 weight layout for an (R x K) matrix:
//   swz[ (((r>>6)*(K>>3) + (k>>3))*64 + (r&63))*8 + (k&7) ] = bf16(W[r][k])
__global__ void swzb_kernel(const void* __restrict__ src, unsigned short* __restrict__ dst,
                            int R, int Ks, int Kt, int c0, const int* __restrict__ flagp)
{
  int i = blockIdx.x * 256 + threadIdx.x;
  if (i >= R * Ks) return;
  int r = i / Ks;
  int k = i - r * Ks;
  int kk = k + c0;
  float v = load_any(src, i, *flagp);
  __hip_bfloat16 bv = __float2bfloat16(v);
  dst[(((size_t)(r >> 6) * (size_t)(Kt >> 3) + (size_t)(kk >> 3)) * 64 + (r & 63)) * 8 + (kk & 7)] =
      *(unsigned short*)&bv;
}

// one full row r of an (R x K) swizzled bf16 matrix, x in LDS (used by proj / small dots)
template<int K>
__device__ __forceinline__ float dot1w(const unsigned short* __restrict__ w, int r,
                                       const float* __restrict__ xs)
{
  constexpr int KC = K >> 3;
  const uint4* __restrict__ p = (const uint4*)w + (size_t)(r >> 6) * KC * 64 + (r & 63);
  float a = 0.0f;
  #pragma unroll 4
  for (int kc = 0; kc < KC; ++kc) {
    const uint4 q = p[(size_t)kc * 64];
    const float4 x0 = *(const float4*)(xs + kc * 8);
    const float4 x1 = *(const float4*)(xs + kc * 8 + 4);
    a += blo(q.x)*x0.x + bhi(q.x)*x0.y + blo(q.y)*x0.z + bhi(q.y)*x0.w
       + blo(q.z)*x1.x + bhi(q.z)*x1.y + blo(q.w)*x1.z + bhi(q.w)*x1.w;
  }
  return a;
}

// Split-K 4-gate partial dot: rows {g*256+j, g=0..3} of a (1024 x K) swizzled matrix,
// K-slice q of 4 (SL uint4-cols each). One LDS x-read feeds 4 weight streams.
// KC = total uint4 cols (K/8), SL = KC/4.
template<int KC, int SL>
__device__ __forceinline__ void dot4s(const unsigned short* __restrict__ w, int j, int q,
                                      const float* __restrict__ xsl, float out4[4])
{
  const int lane = j & 63, wq = j >> 6;
  const uint4* __restrict__ p0 = (const uint4*)w + ((size_t)(wq     ) * KC + q * SL) * 64 + lane;
  const uint4* __restrict__ p1 = (const uint4*)w + ((size_t)(wq + 4 ) * KC + q * SL) * 64 + lane;
  const uint4* __restrict__ p2 = (const uint4*)w + ((size_t)(wq + 8 ) * KC + q * SL) * 64 + lane;
  const uint4* __restrict__ p3 = (const uint4*)w + ((size_t)(wq + 12) * KC + q * SL) * 64 + lane;
  float a0 = 0.0f, a1 = 0.0f, a2 = 0.0f, a3 = 0.0f;
  #pragma unroll 4
  for (int kc = 0; kc < SL; ++kc) {
    const float4 x0 = *(const float4*)(xsl + kc * 8);
    const float4 x1 = *(const float4*)(xsl + kc * 8 + 4);
    uint4 qq;
    qq = p0[(size_t)kc * 64];
    a0 += blo(qq.x)*x0.x + bhi(qq.x)*x0.y + blo(qq.y)*x0.z + bhi(qq.y)*x0.w
        + blo(qq.z)*x1.x + bhi(qq.z)*x1.y + blo(qq.w)*x1.z + bhi(qq.w)*x1.w;
    qq = p1[(size_t)kc * 64];
    a1 += blo(qq.x)*x0.x + bhi(qq.x)*x0.y + blo(qq.y)*x0.z + bhi(qq.y)*x0.w
        + blo(qq.z)*x1.x + bhi(qq.z)*x1.y + blo(qq.w)*x1.z + bhi(qq.w)*x1.w;
    qq = p2[(size_t)kc * 64];
    a2 += blo(qq.x)*x0.x + bhi(qq.x)*x0.y + blo(qq.y)*x0.z + bhi(qq.y)*x0.w
        + blo(qq.z)*x1.x + bhi(qq.z)*x1.y + blo(qq.w)*x1.z + bhi(qq.w)*x1.w;
    qq = p3[(size_t)kc * 64];
    a3 += blo(qq.x)*x0.x + bhi(qq.x)*x0.y + blo(qq.y)*x0.z + bhi(qq.y)*x0.w
        + blo(qq.z)*x1.x + bhi(qq.z)*x1.y + blo(qq.w)*x1.z + bhi(qq.w)*x1.w;
  }
  out4[0] = a0; out4[1] = a1; out4[2] = a2; out4[3] = a3;
}

// Encoder layer 0: 128 blocks x 1024 threads, split-K dot4. Cat weight K=512 (KC=64, SL=16).
__global__ __launch_bounds__(1024, 1) void enc0_kernel(
    const int* __restrict__ src, const float* __restrict__ emb_f,
    const unsigned short* __restrict__ wF, const unsigned short* __restrict__ wB,
    const float* __restrict__ bF, const float* __restrict__ bB,
    float* __restrict__ f0, float* __restrict__ b0)
{
  const int blk = blockIdx.x, dir = blk >> 6, b = blk & 63, tid = threadIdx.x;
  const unsigned short* w = dir ? wB : wF;
  const float* bi = dir ? bB : bF;
  float* outp = dir ? b0 : f0;
  __shared__ __align__(16) float xs[512];
  __shared__ __align__(16) float work4[4096];
  const int q = tid >> 8, j = tid & 255;
  float bias_g[4];
  if (tid < 256) {
    #pragma unroll
    for (int g = 0; g < 4; ++g) bias_g[g] = bi[g * 256 + tid];
    xs[256 + tid] = 0.0f;
  }
  float c = 0.0f, h = 0.0f;
  const size_t bS = (size_t)b * S_;
  for (int t = 0; t < S_; ++t) {
    const int tp = dir ? (S_ - 1 - t) : t;
    const int tok = src[bS + tp];
    if (tid < 256) xs[tid] = emb_f[(size_t)tok * D_ + tid];
    __syncthreads();
    float o4[4];
    dot4s<64, 16>(w, j, q, xs + q * 128, o4);
    #pragma unroll
    for (int g = 0; g < 4; ++g) work4[(g * 4 + q) * 256 + j] = o4[g];
    __syncthreads();
    if (tid < 256) {
      float gv[4];
      #pragma unroll
      for (int g = 0; g < 4; ++g)
        gv[g] = work4[(g*4+0)*256 + tid] + work4[(g*4+1)*256 + tid]
              + work4[(g*4+2)*256 + tid] + work4[(g*4+3)*256 + tid] + bias_g[g];
      cellupd(gv[0], gv[1], gv[2], gv[3], c, h);
      xs[256 + tid] = h;
      outp[(bS + tp) * H_ + tid] = h;
    }
    __syncthreads();
  }
}

// Encoder layer 1: K=768 (KC=96, SL=24). Emits final (h,c) per dir.
__global__ __launch_bounds__(1024, 1) void enc1_kernel(
    const float* __restrict__ f0, const float* __restrict__ b0,
    const unsigned short* __restrict__ wF, const unsigned short* __restrict__ wB,
    const float* __restrict__ bF, const float* __restrict__ bB,
    float* __restrict__ enc_out, float* __restrict__ hcbuf)
{
  const int blk = blockIdx.x, dir = blk >> 6, b = blk & 63, tid = threadIdx.x;
  const unsigned short* w = dir ? wB : wF;
  const float* bi = dir ? bB : bF;
  __shared__ __align__(16) float xs[768];
  __shared__ __align__(16) float work4[4096];
  const int q = tid >> 8, j = tid & 255;
  float bias_g[4];
  if (tid < 256) {
    #pragma unroll
    for (int g = 0; g < 4; ++g) bias_g[g] = bi[g * 256 + tid];
    xs[512 + tid] = 0.0f;
  }
  float c = 0.0f, h = 0.0f;
  const size_t bS = (size_t)b * S_;
  for (int t = 0; t < S_; ++t) {
    const int tp = dir ? (S_ - 1 - t) : t;
    const size_t row = (bS + tp) * (size_t)H_;
    if (tid < 512) {
      const int jj = tid & 255;
      xs[tid] = (tid < 256) ? f0[row + jj] : b0[row + jj];
    }
    __syncthreads();
    float o4[4];
    dot4s<96, 24>(w, j, q, xs + q * 192, o4);
    #pragma unroll
    for (int g = 0; g < 4; ++g) work4[(g * 4 + q) * 256 + j] = o4[g];
    __syncthreads();
    if (tid < 256) {
      float gv[4];
      #pragma unroll
      for (int g = 0; g < 4; ++g)
        gv[g] = work4[(g*4+0)*256 + tid] + work4[(g*4+1)*256 + tid]
              + work4[(g*4+2)*256 + tid] + work4[(g*4+3)*256 + tid] + bias_g[g];
      cellupd(gv[0], gv[1], gv[2], gv[3], c, h);
      xs[512 + tid] = h;
      enc_out[(bS + tp) * 512 + dir * 256 + tid] = h;
    }
    __syncthreads();
  }
  if (tid < 256) {
    const int BH = B_ * H_;
    float* hout = hcbuf + (dir ? 2 * BH : 0);
    hout[(size_t)b * H_ + tid]      = h;
    hout[BH + (size_t)b * H_ + tid] = c;
  }
}

// proj (unchanged)
__global__ __launch_bounds__(256) void proj_kernel(
    const float* __restrict__ enc_out, const float* __restrict__ hcbuf,
    const unsigned short* __restrict__ wenc_s,
    const unsigned short* __restrict__ hpw_s, const unsigned short* __restrict__ cpw_s,
    const float* __restrict__ hpb_f, const float* __restrict__ cpb_f,
    float* __restrict__ epT, float* __restrict__ h0c0)
{
  __shared__ __align__(16) float xs[16 * 512];
  const int blk = blockIdx.x, tid = threadIdx.x;
  if (blk < 1024) {
    const int b = blk >> 4, s0 = (blk & 15) * 16;
    const float* srcp = enc_out + ((size_t)b * S_ + s0) * 512;
    for (int i = tid; i < 16 * 512; i += 256) xs[i] = srcp[i];
    __syncthreads();
    float acc[16];
    #pragma unroll
    for (int r = 0; r < 16; ++r) acc[r] = 0.0f;
    const uint4* p = (const uint4*)wenc_s + (size_t)(tid >> 6) * 64 * 64 + (tid & 63);
    for (int kc = 0; kc < 64; ++kc) {
      const uint4 q = p[(size_t)kc * 64];
      const float w0=blo(q.x), w1=bhi(q.x), w2=blo(q.y), w3=bhi(q.y),
                  w4=blo(q.z), w5=bhi(q.z), w6=blo(q.w), w7=bhi(q.w);
      #pragma unroll
      for (int r = 0; r < 16; ++r) {
        const float4 x0 = *(const float4*)(xs + r * 512 + kc * 8);
        const float4 x1 = *(const float4*)(xs + r * 512 + kc * 8 + 4);
        acc[r] += w0*x0.x + w1*x0.y + w2*x0.z + w3*x0.w + w4*x1.x + w5*x1.y + w6*x1.z + w7*x1.w;
      }
    }
    float* dst = epT + ((size_t)b * S_ + (size_t)tid) * 256 + s0;
    #pragma unroll
    for (int r = 0; r < 16; ++r) dst[r] = acc[r];
  } else {
    const int b = blk - 1024;
    const int BH = B_ * H_;
    xs[tid]        = hcbuf[(size_t)b * H_ + tid];
    xs[256 + tid]  = hcbuf[2 * BH + (size_t)b * H_ + tid];
    xs[512 + tid]  = hcbuf[BH + (size_t)b * H_ + tid];
    xs[768 + tid]  = hcbuf[3 * BH + (size_t)b * H_ + tid];
    __syncthreads();
    const float hv = dot1w<512>(hpw_s, tid, xs)       + hpb_f[tid];
    const float cv = dot1w<512>(cpw_s, tid, xs + 512) + cpb_f[tid];
    h0c0[(size_t)b * H_ + tid]              = tanhfast(hv);
    h0c0[(size_t)BH + (size_t)b * H_ + tid] = tanhfast(cv);
  }
}

// Decoder: 64 blocks x 1024 threads, single CU per batch (no cross-CU sync), split-K cells.
__global__ __launch_bounds__(1024, 1) void dec_kernel(
    const int* __restrict__ src, const int* __restrict__ tgt, const float* __restrict__ emb_f,
    const unsigned short* __restrict__ d0_s, const unsigned short* __restrict__ d1_s,
    const unsigned short* __restrict__ wdec_s,
    const float* __restrict__ d0b, const float* __restrict__ d1b,
    const float* __restrict__ attv_f,
    const float* __restrict__ enc_out, const float* __restrict__ epT,
    const float* __restrict__ h0c0,
    float* __restrict__ dec_h)
{
  const int b = blockIdx.x, tid = threadIdx.x;
  __shared__ __align__(16) float xcat[1024];  // [xt | ctx(512) | hl0]
  __shared__ __align__(16) float hcat[512];   // [hl0 | hl1]
  __shared__ __align__(16) float work4[4096]; // partials (all phases)
  __shared__ __align__(16) float qs[256];
  __shared__ __align__(16) float sc[256];
  __shared__ __align__(16) float vv[256];
  __shared__ __align__(16) float mb[256];
  __shared__ float red[8];

  const int q = tid >> 8, j = tid & 255;
  float cl0 = 0.0f, cl1 = 0.0f;
  float b0g[4], b1g[4];
  if (tid < 256) {
    #pragma unroll
    for (int g = 0; g < 4; ++g) { b0g[g] = d0b[g * 256 + tid]; b1g[g] = d1b[g * 256 + tid]; }
    const float h0v = h0c0[(size_t)b * H_ + tid];
    const float c0v = h0c0[(size_t)B_ * H_ + (size_t)b * H_ + tid];
    cl0 = c0v; cl1 = c0v;
    xcat[768 + tid] = h0v;
    hcat[tid]       = h0v;
    hcat[256 + tid] = h0v;
    vv[tid] = attv_f[tid];
    mb[tid] = (src[(size_t)b * S_ + tid] == 0) ? -1e30f : 0.0f;
  }
  __syncthreads();

  const float* eo = enc_out + (size_t)b * S_ * 512;
  const float4* eo4 = (const float4*)eo;
  const float* ep = epT + (size_t)b * 65536;
  const int wid = tid >> 6;

  for (int t = 0; t < T_; ++t) {
    // ---- phase A: q = hl1 @ Wdec.T (K split 4x64); stage xt embed
    {
      const uint4* p = (const uint4*)wdec_s + ((size_t)(j >> 6) * 32 + q * 8) * 64 + (j & 63);
      const float* xq = hcat + 256 + q * 64;
      float a = 0.0f;
      #pragma unroll
      for (int i = 0; i < 8; ++i) {
        const uint4 qq = p[(size_t)i * 64];
        const float4 x0 = *(const float4*)(xq + i * 8);
        const float4 x1 = *(const float4*)(xq + i * 8 + 4);
        a += blo(qq.x)*x0.x + bhi(qq.x)*x0.y + blo(qq.y)*x0.z + bhi(qq.y)*x0.w
           + blo(qq.z)*x1.x + bhi(qq.z)*x1.y + blo(qq.w)*x1.z + bhi(qq.w)*x1.w;
      }
      work4[q * 256 + j] = a;
    }
    __syncthreads();
    if (tid < 256) {
      qs[tid] = work4[tid] + work4[256 + tid] + work4[512 + tid] + work4[768 + tid];
    } else if (tid < 512) {
      const int jj = tid - 256;
      const int tok = tgt[(size_t)b * 257 + t];
      xcat[jj] = emb_f[(size_t)tok * 256 + jj];
    }
    __syncthreads();
    // ---- phase B1: scores, jj split 4x64
    {
      const float* epq = ep + (size_t)(q * 64) * 256 + j;
      const float* vq = vv + q * 64;
      const float* qq_ = qs + q * 64;
      float a = 0.0f;
      #pragma unroll 4
      for (int i = 0; i < 64; ++i)
        a += vq[i] * tanhfast(epq[(size_t)i * 256] + qq_[i]);
      work4[q * 256 + j] = a;
    }
    __syncthreads();
    float e = 0.0f, pexp = 0.0f;
    if (tid < 256) {
      e = work4[tid] + work4[256 + tid] + work4[512 + tid] + work4[768 + tid] + mb[tid];
      float m = wredmax(e);
      if ((tid & 63) == 0) red[wid] = m;
    }
    __syncthreads();
    if (tid < 256) {
      const float m = fmaxf(fmaxf(red[0], red[1]), fmaxf(red[2], red[3]));
      pexp = __expf(e - m);
      float sm = wredsum(pexp);
      if ((tid & 63) == 0) red[4 + wid] = sm;
    }
    __syncthreads();
    if (tid < 256) {
      const float sm = (red[4] + red[5]) + (red[6] + red[7]);
      sc[tid] = pexp / sm;
    }
    __syncthreads();
    // ---- phase B2: ctx, float4 over d, s split 8x32
    {
      const int sc8 = tid >> 7, d4 = tid & 127;
      float4 acc = make_float4(0.f, 0.f, 0.f, 0.f);
      const float* scp = sc + sc8 * 32;
      const float4* eop = eo4 + (size_t)(sc8 * 32) * 128 + d4;
      #pragma unroll 4
      for (int i = 0; i < 32; ++i) {
        const float w_ = scp[i];
        const float4 v = eop[(size_t)i * 128];
        acc.x += w_ * v.x; acc.y += w_ * v.y; acc.z += w_ * v.z; acc.w += w_ * v.w;
      }
      *(float4*)(work4 + (sc8 * 128 + d4) * 4) = acc;
    }
    __syncthreads();
    if (tid < 128) {
      float4 a = *(const float4*)(work4 + tid * 4);
      #pragma unroll
      for (int i = 1; i < 8; ++i) {
        const float4 v = *(const float4*)(work4 + (i * 128 + tid) * 4);
        a.x += v.x; a.y += v.y; a.z += v.z; a.w += v.w;
      }
      *(float4*)(xcat + 256 + tid * 4) = a;
    }
    __syncthreads();
    // ---- phase C0: cell0, K=1024 (KC=128, SL=32)
    {
      float o4[4];
      dot4s<128, 32>(d0_s, j, q, xcat + q * 256, o4);
      #pragma unroll
      for (int g = 0; g < 4; ++g) work4[(g * 4 + q) * 256 + j] = o4[g];
    }
    __syncthreads();
    if (tid < 256) {
      float gv[4];
      #pragma unroll
      for (int g = 0; g < 4; ++g)
        gv[g] = work4[(g*4+0)*256 + tid] + work4[(g*4+1)*256 + tid]
              + work4[(g*4+2)*256 + tid] + work4[(g*4+3)*256 + tid] + b0g[g];
      float hn0;
      cellupd(gv[0], gv[1], gv[2], gv[3], cl0, hn0);
      xcat[768 + tid] = hn0;
      hcat[tid]       = hn0;
    }
    __syncthreads();
    // ---- phase C1: cell1, K=512 (KC=64, SL=16)
    {
      float o4[4];
      dot4s<64, 16>(d1_s, j, q, hcat + q * 128, o4);
      #pragma unroll
      for (int g = 0; g < 4; ++g) work4[(g * 4 + q) * 256 + j] = o4[g];
    }
    __syncthreads();
    if (tid < 256) {
      float gv[4];
      #pragma unroll
      for (int g = 0; g < 4; ++g)
        gv[g] = work4[(g*4+0)*256 + tid] + work4[(g*4+1)*256 + tid]
              + work4[(g*4+2)*256 + tid] + work4[(g*4+3)*256 + tid] + b1g[g];
      float hn1;
      cellupd(gv[0], gv[1], gv[2], gv[3], cl1, hn1);
      hcat[256 + tid] = hn1;
      dec_h[((size_t)b * T_ + t) * H_ + tid] = hn1;
    }
    __syncthreads();
  }
}

// out (unchanged)
__global__ __launch_bounds__(256) void out_kernel(
    const float* __restrict__ dec_h, const unsigned short* __restrict__ emb_s,
    void* __restrict__ out, const int* __restrict__ flagp)
{
  __shared__ __align__(16) float hs[16 * 256];
  const int blk = blockIdx.x, tid = threadIdx.x;
  const int isf32 = *flagp;
  const float* srcp = dec_h + (size_t)blk * (16 * 256);
  for (int i = tid; i < 16 * 256; i += 256) hs[i] = srcp[i];
  __syncthreads();
  #pragma unroll
  for (int vi = 0; vi < 4; ++vi) {
    const int v = tid + vi * 256;
    if (v < V_) {
      const uint4* p = (const uint4*)emb_s + (size_t)(v >> 6) * 32 * 64 + (v & 63);
      float acc[16];
      #pragma unroll
      for (int r = 0; r < 16; ++r) acc[r] = 0.0f;
      for (int kc = 0; kc < 32; ++kc) {
        const uint4 q = p[(size_t)kc * 64];
        const float w0=blo(q.x), w1=bhi(q.x), w2=blo(q.y), w3=bhi(q.y),
                    w4=blo(q.z), w5=bhi(q.z), w6=blo(q.w), w7=bhi(q.w);
        #pragma unroll
        for (int r = 0; r < 16; ++r) {
          const float4 x0 = *(const float4*)(hs + r * 256 + kc * 8);
          const float4 x1 = *(const float4*)(hs + r * 256 + kc * 8 + 4);
          acc[r] += w0*x0.x + w1*x0.y + w2*x0.z + w3*x0.w + w4*x1.x + w5*x1.y + w6*x1.z + w7*x1.w;
        }
      }
      const size_t rowbase = (size_t)blk * 16;
      if (isf32) {
        float* o = (float*)out;
        #pragma unroll
        for (int r = 0; r < 16; ++r) o[(rowbase + r) * V_ + v] = acc[r];
      } else {
        __hip_bfloat16* o = (__hip_bfloat16*)out;
        #pragma unroll
        for (int r = 0; r < 16; ++r) o[(rowbase + r) * V_ + v] = __float2bfloat16(acc[r]);
      }
    }
  }
}

extern "C" void kernel_launch(void* const* d_in, const int* in_sizes, int n_in,
                              void* d_out, int out_size, void* d_ws, size_t ws_size,
                              hipStream_t stream)
{
  (void)in_sizes; (void)n_in; (void)out_size; (void)ws_size;
  const int* src = (const int*)d_in[0];
  const int* tgt = (const int*)d_in[1];

  char* base = (char*)d_ws;
  int* flag = (int*)base;
  float* ws = (float*)(base + 256);
  size_t off = 0;
  float* f0      = ws + off; off += (size_t)B_ * S_ * H_;
  float* b0      = ws + off; off += (size_t)B_ * S_ * H_;
  float* enc_out = ws + off; off += (size_t)B_ * S_ * 2 * H_;
  float* hcbuf   = ws + off; off += 4 * (size_t)B_ * H_;
  float* h0c0    = ws + off; off += 2 * (size_t)B_ * H_;
  float* emb_f   = ws + off; off += (size_t)V_ * D_;
  float* e0f_b   = ws + off; off += 1024;
  float* e0b_b   = ws + off; off += 1024;
  float* e1f_b   = ws + off; off += 1024;
  float* e1b_b   = ws + off; off += 1024;
  float* d0_b    = ws + off; off += 1024;
  float* d1_b    = ws + off; off += 1024;
  float* hpb_f   = ws + off; off += 256;
  float* cpb_f   = ws + off; off += 256;
  float* attv_f  = ws + off; off += 256;
  unsigned short* us = (unsigned short*)(ws + off);
  size_t uo = 0;
  unsigned short* e0f_s  = us + uo; uo += (size_t)1024 * 512;
  unsigned short* e0b_s  = us + uo; uo += (size_t)1024 * 512;
  unsigned short* e1f_s  = us + uo; uo += (size_t)1024 * 768;
  unsigned short* e1b_s  = us + uo; uo += (size_t)1024 * 768;
  unsigned short* d0_s   = us + uo; uo += (size_t)1024 * 1024;
  unsigned short* d1_s   = us + uo; uo += (size_t)1024 * 512;
  unsigned short* wdec_s = us + uo; uo += (size_t)256 * 256;
  unsigned short* wenc_s = us + uo; uo += (size_t)256 * 512;
  unsigned short* hpw_s  = us + uo; uo += (size_t)256 * 512;
  unsigned short* cpw_s  = us + uo; uo += (size_t)256 * 512;
  unsigned short* emb_s  = us + uo; uo += (size_t)1024 * 256;
  float* dec_h = f0;
  float* epT   = b0;

  hipLaunchKernelGGL(probe_kernel, dim3(1), dim3(64), 0, stream,
                     (const unsigned short*)d_in[3], flag);

  auto swz = [&](int idx, unsigned short* dst, int R, int Ks, int Kt, int c0){
    const int n = R * Ks;
    hipLaunchKernelGGL(swzb_kernel, dim3((n + 255) / 256), dim3(256), 0, stream,
                       d_in[idx], dst, R, Ks, Kt, c0, flag);
  };
  auto bias2 = [&](int ia, int ib, float* dst, int n){
    hipLaunchKernelGGL(bias_kernel, dim3((n + 255) / 256), dim3(256), 0, stream,
                       d_in[ia], d_in[ib], dst, n, flag);
  };

  hipLaunchKernelGGL(conv_kernel, dim3((V_ * D_ + 255) / 256), dim3(256), 0, stream,
                     d_in[2], emb_f, V_ * D_, flag);
  hipLaunchKernelGGL(conv_kernel, dim3(1), dim3(256), 0, stream, d_in[28], hpb_f, 256, flag);
  hipLaunchKernelGGL(conv_kernel, dim3(1), dim3(256), 0, stream, d_in[30], cpb_f, 256, flag);
  hipLaunchKernelGGL(conv_kernel, dim3(1), dim3(256), 0, stream, d_in[33], attv_f, 256, flag);
  bias2(5, 6, e0f_b, 1024);   bias2(9, 10, e0b_b, 1024);
  bias2(13, 14, e1f_b, 1024); bias2(17, 18, e1b_b, 1024);
  bias2(21, 22, d0_b, 1024);  bias2(25, 26, d1_b, 1024);
  swz(3,  e0f_s, 1024, 256, 512, 0);   swz(4,  e0f_s, 1024, 256, 512, 256);
  swz(7,  e0b_s, 1024, 256, 512, 0);   swz(8,  e0b_s, 1024, 256, 512, 256);
  swz(11, e1f_s, 1024, 512, 768, 0);   swz(12, e1f_s, 1024, 256, 768, 512);
  swz(15, e1b_s, 1024, 512, 768, 0);   swz(16, e1b_s, 1024, 256, 768, 512);
  swz(19, d0_s, 1024, 768, 1024, 0);   swz(20, d0_s, 1024, 256, 1024, 768);
  swz(23, d1_s, 1024, 256, 512, 0);    swz(24, d1_s, 1024, 256, 512, 256);
  swz(32, wdec_s, 256, 256, 256, 0);
  swz(31, wenc_s, 256, 512, 512, 0);
  swz(27, hpw_s, 256, 512, 512, 0);
  swz(29, cpw_s, 256, 512, 512, 0);
  swz(2,  emb_s, 1000, 256, 256, 0);

  hipLaunchKernelGGL(enc0_kernel, dim3(128), dim3(1024), 0, stream,
                     src, emb_f, e0f_s, e0b_s, e0f_b, e0b_b, f0, b0);
  hipLaunchKernelGGL(enc1_kernel, dim3(128), dim3(1024), 0, stream,
                     f0, b0, e1f_s, e1b_s, e1f_b, e1b_b, enc_out, hcbuf);
  hipLaunchKernelGGL(proj_kernel, dim3(1088), dim3(256), 0, stream,
                     enc_out, hcbuf, wenc_s, hpw_s, cpw_s, hpb_f, cpb_f, epT, h0c0);
  hipLaunchKernelGGL(dec_kernel, dim3(64), dim3(1024), 0, stream,
                     src, tgt, emb_f, d0_s, d1_s, wdec_s, d0_b, d1_b, attv_f,
                     enc_out, epT, h0c0, dec_h);
  hipLaunchKernelGGL(out_kernel, dim3(1024), dim3(256), 0, stream,
                     dec_h, emb_s, d_out, flag);
}

// Round 6
// 17780.553 us; speedup vs baseline: 2.6410x; 1.2933x over previous
//
#include <hip/hip_runtime.h>
#include <hip/hip_bf16.h>
#include <stdint.h>

#define B_ 64
#define S_ 256
#define T_ 256
#define D_ 256
#define H_ 256
#define V_ 1000

__device__ __forceinline__ float blo(unsigned u){ return __uint_as_float(u << 16); }
__device__ __forceinline__ float bhi(unsigned u){ return __uint_as_float(u & 0xffff0000u); }
__device__ __forceinline__ float sigm(float x){ return 1.0f / (1.0f + __expf(-x)); }
__device__ __forceinline__ float tanhfast(float x){ float e = __expf(2.0f * x); return 1.0f - 2.0f / (e + 1.0f); }

__device__ __forceinline__ void cellupd(float a0, float a1, float a2, float a3, float& c, float& h){
  float cn = sigm(a1) * c + sigm(a0) * tanhfast(a2);
  c = cn;
  h = sigm(a3) * tanhfast(cn);
}

__device__ __forceinline__ float wredmax(float v){
  #pragma unroll
  for (int o = 32; o > 0; o >>= 1) v = fmaxf(v, __shfl_xor(v, o));
  return v;
}
__device__ __forceinline__ float wredsum(float v){
  #pragma unroll
  for (int o = 32; o > 0; o >>= 1) v += __shfl_xor(v, o);
  return v;
}

// ---------------- dtype probe ----------------
__global__ void probe_kernel(const unsigned short* __restrict__ w, int* __restrict__ flag)
{
  int cnt = 0;
  for (int i = threadIdx.x; i < 4096; i += 64) {
    unsigned e = (w[i] >> 7) & 0xFFu;
    if (e >= 0xC0u) cnt++;
  }
  #pragma unroll
  for (int o = 32; o > 0; o >>= 1) cnt += __shfl_xor(cnt, o);
  if (threadIdx.x == 0) *flag = (cnt > 32) ? 1 : 0;
}

__device__ __forceinline__ float load_any(const void* src, int i, int isf32){
  return isf32 ? ((const float*)src)[i]
               : __uint_as_float(((unsigned)((const unsigned short*)src)[i]) << 16);
}

__global__ void conv_kernel(const void* __restrict__ src, float* __restrict__ dst, int n,
                            const int* __restrict__ flagp)
{
  int i = blockIdx.x * 256 + threadIdx.x;
  if (i >= n) return;
  dst[i] = load_any(src, i, *flagp);
}

__global__ void bias_kernel(const void* __restrict__ a, const void* __restrict__ bsrc,
                            float* __restrict__ dst, int n, const int* __restrict__ flagp)
{
  int i = blockIdx.x * 256 + threadIdx.x;
  if (i >= n) return;
  int f = *flagp;
  dst[i] = load_any(a, i, f) + load_any(bsrc, i, f);
}

// Swizzled bf16 weight layout for an (R x K) matrix:
//   swz[ (((R'>>6)*(K>>3) + (k>>3))*64 + (R'&63))*8 + (k&7) ] = bf16(W[r][k])
// perm=1 (cell matrices): R'(g=r>>8, j=r&255) = (j>>4)*64 + g*16 + (j&15),
// so each 64-row group holds all 4 gates of 16 consecutive j.
__global__ void swzb_kernel(const void* __restrict__ src, unsigned short* __restrict__ dst,
                            int R, int Ks, int Kt, int c0, int perm, const int* __restrict__ flagp)
{
  int i = blockIdx.x * 256 + threadIdx.x;
  if (i >= R * Ks) return;
  int r = i / Ks;
  int k = i - r * Ks;
  int kk = k + c0;
  int Rr = r;
  if (perm) {
    int g = r >> 8, j = r & 255;
    Rr = ((j >> 4) << 6) + (g << 4) + (j & 15);
  }
  float v = load_any(src, i, *flagp);
  __hip_bfloat16 bv = __float2bfloat16(v);
  dst[(((size_t)(Rr >> 6) * (size_t)(Kt >> 3) + (size_t)(kk >> 3)) * 64 + (Rr & 63)) * 8 + (kk & 7)] =
      *(unsigned short*)&bv;
}

// one full row r of an (R x K) swizzled bf16 matrix, x in LDS
template<int K>
__device__ __forceinline__ float dot1w(const unsigned short* __restrict__ w, int r,
                                       const float* __restrict__ xs)
{
  constexpr int KC = K >> 3;
  const uint4* __restrict__ p = (const uint4*)w + (size_t)(r >> 6) * KC * 64 + (r & 63);
  float a = 0.0f;
  #pragma unroll 4
  for (int kc = 0; kc < KC; ++kc) {
    const uint4 q = p[(size_t)kc * 64];
    const float4 x0 = *(const float4*)(xs + kc * 8);
    const float4 x1 = *(const float4*)(xs + kc * 8 + 4);
    a += blo(q.x)*x0.x + bhi(q.x)*x0.y + blo(q.y)*x0.z + bhi(q.y)*x0.w
       + blo(q.z)*x1.x + bhi(q.z)*x1.y + blo(q.w)*x1.z + bhi(q.w)*x1.w;
  }
  return a;
}

// Split-K 4-gate partial dot (encoders): rows {g*256+j}, K-slice q of 4.
template<int KC, int SL>
__device__ __forceinline__ void dot4s(const unsigned short* __restrict__ w, int j, int q,
                                      const float* __restrict__ xsl, float out4[4])
{
  const int lane = j & 63, wq = j >> 6;
  const uint4* __restrict__ p0 = (const uint4*)w + ((size_t)(wq     ) * KC + q * SL) * 64 + lane;
  const uint4* __restrict__ p1 = (const uint4*)w + ((size_t)(wq + 4 ) * KC + q * SL) * 64 + lane;
  const uint4* __restrict__ p2 = (const uint4*)w + ((size_t)(wq + 8 ) * KC + q * SL) * 64 + lane;
  const uint4* __restrict__ p3 = (const uint4*)w + ((size_t)(wq + 12) * KC + q * SL) * 64 + lane;
  float a0 = 0.0f, a1 = 0.0f, a2 = 0.0f, a3 = 0.0f;
  #pragma unroll 4
  for (int kc = 0; kc < SL; ++kc) {
    const float4 x0 = *(const float4*)(xsl + kc * 8);
    const float4 x1 = *(const float4*)(xsl + kc * 8 + 4);
    uint4 qq;
    qq = p0[(size_t)kc * 64];
    a0 += blo(qq.x)*x0.x + bhi(qq.x)*x0.y + blo(qq.y)*x0.z + bhi(qq.y)*x0.w
        + blo(qq.z)*x1.x + bhi(qq.z)*x1.y + blo(qq.w)*x1.z + bhi(qq.w)*x1.w;
    qq = p1[(size_t)kc * 64];
    a1 += blo(qq.x)*x0.x + bhi(qq.x)*x0.y + blo(qq.y)*x0.z + bhi(qq.y)*x0.w
        + blo(qq.z)*x1.x + bhi(qq.z)*x1.y + blo(qq.w)*x1.z + bhi(qq.w)*x1.w;
    qq = p2[(size_t)kc * 64];
    a2 += blo(qq.x)*x0.x + bhi(qq.x)*x0.y + blo(qq.y)*x0.z + bhi(qq.y)*x0.w
        + blo(qq.z)*x1.x + bhi(qq.z)*x1.y + blo(qq.w)*x1.z + bhi(qq.w)*x1.w;
    qq = p3[(size_t)kc * 64];
    a3 += blo(qq.x)*x0.x + bhi(qq.x)*x0.y + blo(qq.y)*x0.z + bhi(qq.y)*x0.w
        + blo(qq.z)*x1.x + bhi(qq.z)*x1.y + blo(qq.w)*x1.z + bhi(qq.w)*x1.w;
  }
  out4[0] = a0; out4[1] = a1; out4[2] = a2; out4[3] = a3;
}

// ---------------- encoder (unchanged from round 5) ----------------
__global__ __launch_bounds__(1024, 1) void enc0_kernel(
    const int* __restrict__ src, const float* __restrict__ emb_f,
    const unsigned short* __restrict__ wF, const unsigned short* __restrict__ wB,
    const float* __restrict__ bF, const float* __restrict__ bB,
    float* __restrict__ f0, float* __restrict__ b0)
{
  const int blk = blockIdx.x, dir = blk >> 6, b = blk & 63, tid = threadIdx.x;
  const unsigned short* w = dir ? wB : wF;
  const float* bi = dir ? bB : bF;
  float* outp = dir ? b0 : f0;
  __shared__ __align__(16) float xs[512];
  __shared__ __align__(16) float work4[4096];
  const int q = tid >> 8, j = tid & 255;
  float bias_g[4];
  if (tid < 256) {
    #pragma unroll
    for (int g = 0; g < 4; ++g) bias_g[g] = bi[g * 256 + tid];
    xs[256 + tid] = 0.0f;
  }
  float c = 0.0f, h = 0.0f;
  const size_t bS = (size_t)b * S_;
  for (int t = 0; t < S_; ++t) {
    const int tp = dir ? (S_ - 1 - t) : t;
    const int tok = src[bS + tp];
    if (tid < 256) xs[tid] = emb_f[(size_t)tok * D_ + tid];
    __syncthreads();
    float o4[4];
    dot4s<64, 16>(w, j, q, xs + q * 128, o4);
    #pragma unroll
    for (int g = 0; g < 4; ++g) work4[(g * 4 + q) * 256 + j] = o4[g];
    __syncthreads();
    if (tid < 256) {
      float gv[4];
      #pragma unroll
      for (int g = 0; g < 4; ++g)
        gv[g] = work4[(g*4+0)*256 + tid] + work4[(g*4+1)*256 + tid]
              + work4[(g*4+2)*256 + tid] + work4[(g*4+3)*256 + tid] + bias_g[g];
      cellupd(gv[0], gv[1], gv[2], gv[3], c, h);
      xs[256 + tid] = h;
      outp[(bS + tp) * H_ + tid] = h;
    }
    __syncthreads();
  }
}

__global__ __launch_bounds__(1024, 1) void enc1_kernel(
    const float* __restrict__ f0, const float* __restrict__ b0,
    const unsigned short* __restrict__ wF, const unsigned short* __restrict__ wB,
    const float* __restrict__ bF, const float* __restrict__ bB,
    float* __restrict__ enc_out, float* __restrict__ hcbuf)
{
  const int blk = blockIdx.x, dir = blk >> 6, b = blk & 63, tid = threadIdx.x;
  const unsigned short* w = dir ? wB : wF;
  const float* bi = dir ? bB : bF;
  __shared__ __align__(16) float xs[768];
  __shared__ __align__(16) float work4[4096];
  const int q = tid >> 8, j = tid & 255;
  float bias_g[4];
  if (tid < 256) {
    #pragma unroll
    for (int g = 0; g < 4; ++g) bias_g[g] = bi[g * 256 + tid];
    xs[512 + tid] = 0.0f;
  }
  float c = 0.0f, h = 0.0f;
  const size_t bS = (size_t)b * S_;
  for (int t = 0; t < S_; ++t) {
    const int tp = dir ? (S_ - 1 - t) : t;
    const size_t row = (bS + tp) * (size_t)H_;
    if (tid < 512) {
      const int jj = tid & 255;
      xs[tid] = (tid < 256) ? f0[row + jj] : b0[row + jj];
    }
    __syncthreads();
    float o4[4];
    dot4s<96, 24>(w, j, q, xs + q * 192, o4);
    #pragma unroll
    for (int g = 0; g < 4; ++g) work4[(g * 4 + q) * 256 + j] = o4[g];
    __syncthreads();
    if (tid < 256) {
      float gv[4];
      #pragma unroll
      for (int g = 0; g < 4; ++g)
        gv[g] = work4[(g*4+0)*256 + tid] + work4[(g*4+1)*256 + tid]
              + work4[(g*4+2)*256 + tid] + work4[(g*4+3)*256 + tid] + bias_g[g];
      cellupd(gv[0], gv[1], gv[2], gv[3], c, h);
      xs[512 + tid] = h;
      enc_out[(bS + tp) * 512 + dir * 256 + tid] = h;
    }
    __syncthreads();
  }
  if (tid < 256) {
    const int BH = B_ * H_;
    float* hout = hcbuf + (dir ? 2 * BH : 0);
    hout[(size_t)b * H_ + tid]      = h;
    hout[BH + (size_t)b * H_ + tid] = c;
  }
}

// proj (unchanged)
__global__ __launch_bounds__(256) void proj_kernel(
    const float* __restrict__ enc_out, const float* __restrict__ hcbuf,
    const unsigned short* __restrict__ wenc_s,
    const unsigned short* __restrict__ hpw_s, const unsigned short* __restrict__ cpw_s,
    const float* __restrict__ hpb_f, const float* __restrict__ cpb_f,
    float* __restrict__ epT, float* __restrict__ h0c0)
{
  __shared__ __align__(16) float xs[16 * 512];
  const int blk = blockIdx.x, tid = threadIdx.x;
  if (blk < 1024) {
    const int b = blk >> 4, s0 = (blk & 15) * 16;
    const float* srcp = enc_out + ((size_t)b * S_ + s0) * 512;
    for (int i = tid; i < 16 * 512; i += 256) xs[i] = srcp[i];
    __syncthreads();
    float acc[16];
    #pragma unroll
    for (int r = 0; r < 16; ++r) acc[r] = 0.0f;
    const uint4* p = (const uint4*)wenc_s + (size_t)(tid >> 6) * 64 * 64 + (tid & 63);
    for (int kc = 0; kc < 64; ++kc) {
      const uint4 q = p[(size_t)kc * 64];
      const float w0=blo(q.x), w1=bhi(q.x), w2=blo(q.y), w3=bhi(q.y),
                  w4=blo(q.z), w5=bhi(q.z), w6=blo(q.w), w7=bhi(q.w);
      #pragma unroll
      for (int r = 0; r < 16; ++r) {
        const float4 x0 = *(const float4*)(xs + r * 512 + kc * 8);
        const float4 x1 = *(const float4*)(xs + r * 512 + kc * 8 + 4);
        acc[r] += w0*x0.x + w1*x0.y + w2*x0.z + w3*x0.w + w4*x1.x + w5*x1.y + w6*x1.z + w7*x1.w;
      }
    }
    float* dst = epT + ((size_t)b * S_ + (size_t)tid) * 256 + s0;
    #pragma unroll
    for (int r = 0; r < 16; ++r) dst[r] = acc[r];
  } else {
    const int b = blk - 1024;
    const int BH = B_ * H_;
    xs[tid]        = hcbuf[(size_t)b * H_ + tid];
    xs[256 + tid]  = hcbuf[2 * BH + (size_t)b * H_ + tid];
    xs[512 + tid]  = hcbuf[BH + (size_t)b * H_ + tid];
    xs[768 + tid]  = hcbuf[3 * BH + (size_t)b * H_ + tid];
    __syncthreads();
    const float hv = dot1w<512>(hpw_s, tid, xs)       + hpb_f[tid];
    const float cv = dot1w<512>(cpw_s, tid, xs + 512) + cpb_f[tid];
    h0c0[(size_t)b * H_ + tid]              = tanhfast(hv);
    h0c0[(size_t)BH + (size_t)b * H_ + tid] = tanhfast(cv);
  }
}

// ---------------- batched decoder: 4 micro-kernels per step ----------------

__global__ void dec_init_kernel(const float* __restrict__ h0c0,
    float* __restrict__ hl0A, float* __restrict__ hl1A,
    float* __restrict__ cl0, float* __restrict__ cl1)
{
  const int i = blockIdx.x * 256 + threadIdx.x;   // 64*256
  const float h = h0c0[i], c = h0c0[B_ * H_ + i];
  hl0A[i] = h; hl1A[i] = h; cl0[i] = c; cl1[i] = c;
}

// K1a: 256 blocks = (b, s-quarter). q computed redundantly per block.
__global__ __launch_bounds__(256) void att_score_kernel(
    const float* __restrict__ hl1r, const unsigned short* __restrict__ wdec_s,
    const float* __restrict__ epT, const float* __restrict__ attv_f,
    const int* __restrict__ src, float* __restrict__ e_sc)
{
  const int blk = blockIdx.x, b = blk >> 2, sq = blk & 3, tid = threadIdx.x;
  __shared__ __align__(16) float hs[256];
  __shared__ __align__(16) float qv[256];
  __shared__ __align__(16) float vvl[256];
  __shared__ __align__(16) float part[4][64];
  hs[tid] = hl1r[b * 256 + tid];
  vvl[tid] = attv_f[tid];
  __syncthreads();
  qv[tid] = dot1w<256>(wdec_s, tid, hs);
  __syncthreads();
  const int s = tid & 63, jq = tid >> 6;
  const float* ep = epT + (size_t)b * 65536 + (size_t)(jq * 64) * 256 + sq * 64 + s;
  float a = 0.0f;
  #pragma unroll 4
  for (int i = 0; i < 64; ++i)
    a += vvl[jq * 64 + i] * tanhfast(ep[(size_t)i * 256] + qv[jq * 64 + i]);
  part[jq][s] = a;
  __syncthreads();
  if (tid < 64) {
    const int sg = sq * 64 + tid;
    float e = part[0][tid] + part[1][tid] + part[2][tid] + part[3][tid];
    if (src[b * 256 + sg] == 0) e = -1e30f;
    e_sc[b * 256 + sg] = e;
  }
}

// K1b: 256 blocks = (b, d-quarter of 128). Softmax redundant per block.
__global__ __launch_bounds__(256) void att_ctx_kernel(
    const float* __restrict__ e_sc, const float* __restrict__ enc_out,
    float* __restrict__ ctxb)
{
  const int blk = blockIdx.x, b = blk >> 2, dq = blk & 3, tid = threadIdx.x;
  __shared__ __align__(16) float ws[256];
  __shared__ __align__(16) float part[2][128];
  __shared__ float red[8];
  const int wid = tid >> 6;
  float e = e_sc[b * 256 + tid];
  float m = wredmax(e);
  if ((tid & 63) == 0) red[wid] = m;
  __syncthreads();
  m = fmaxf(fmaxf(red[0], red[1]), fmaxf(red[2], red[3]));
  float pexp = __expf(e - m);
  float sm = wredsum(pexp);
  if ((tid & 63) == 0) red[4 + wid] = sm;
  __syncthreads();
  sm = (red[4] + red[5]) + (red[6] + red[7]);
  ws[tid] = pexp / sm;
  __syncthreads();
  const int d = tid & 127, sh = tid >> 7;
  const float* eo = enc_out + (size_t)b * (S_ * 512) + (size_t)(sh * 128) * 512 + dq * 128 + d;
  float a = 0.0f;
  #pragma unroll 4
  for (int i = 0; i < 128; ++i)
    a += ws[sh * 128 + i] * eo[(size_t)i * 512];
  part[sh][d] = a;
  __syncthreads();
  if (tid < 128) ctxb[b * 512 + dq * 128 + tid] = part[0][tid] + part[1][tid];
}

// K2 (cell0): 256 blocks = (bg<<4)|rg. rg = 16 j's x 4 gates (permuted rows), bg = 4 batches.
// Thread (lane=permuted row, wq=K-quarter); x staged xT[k][4b], wave-uniform float4 reads.
__global__ __launch_bounds__(256) void cell0_kernel(
    const int* __restrict__ tgt, const float* __restrict__ emb_f,
    const float* __restrict__ ctxb, const float* __restrict__ hl0r,
    const unsigned short* __restrict__ d0p, const float* __restrict__ d0b,
    float* __restrict__ cl0, float* __restrict__ hl0w, int t)
{
  const int blk = blockIdx.x, rg = blk & 15, bg = blk >> 4, tid = threadIdx.x;
  const int lane = tid & 63, wq = tid >> 6;
  __shared__ __align__(16) float xT[1024 * 4];
  __shared__ __align__(16) float part[4 * 64 * 4];
  for (int i = tid; i < 4096; i += 256) {
    const int bb = i >> 10, k = i & 1023;
    const int b = bg * 4 + bb;
    float v;
    if (k < 256)      v = emb_f[(size_t)tgt[b * 257 + t] * 256 + k];
    else if (k < 768) v = ctxb[b * 512 + (k - 256)];
    else              v = hl0r[b * 256 + (k - 768)];
    xT[k * 4 + bb] = v;
  }
  __syncthreads();
  const uint4* __restrict__ p = (const uint4*)d0p + ((size_t)rg * 128 + wq * 32) * 64 + lane;
  const float4* __restrict__ xp = (const float4*)xT + wq * 256;
  float a0 = 0.f, a1 = 0.f, a2 = 0.f, a3 = 0.f;
  #pragma unroll 4
  for (int kc = 0; kc < 32; ++kc) {
    const uint4 q = p[(size_t)kc * 64];
    const float4 x0 = xp[kc*8+0], x1 = xp[kc*8+1], x2 = xp[kc*8+2], x3 = xp[kc*8+3];
    const float4 x4 = xp[kc*8+4], x5 = xp[kc*8+5], x6 = xp[kc*8+6], x7 = xp[kc*8+7];
    float w;
    w = blo(q.x); a0 += w*x0.x; a1 += w*x0.y; a2 += w*x0.z; a3 += w*x0.w;
    w = bhi(q.x); a0 += w*x1.x; a1 += w*x1.y; a2 += w*x1.z; a3 += w*x1.w;
    w = blo(q.y); a0 += w*x2.x; a1 += w*x2.y; a2 += w*x2.z; a3 += w*x2.w;
    w = bhi(q.y); a0 += w*x3.x; a1 += w*x3.y; a2 += w*x3.z; a3 += w*x3.w;
    w = blo(q.z); a0 += w*x4.x; a1 += w*x4.y; a2 += w*x4.z; a3 += w*x4.w;
    w = bhi(q.z); a0 += w*x5.x; a1 += w*x5.y; a2 += w*x5.z; a3 += w*x5.w;
    w = blo(q.w); a0 += w*x6.x; a1 += w*x6.y; a2 += w*x6.z; a3 += w*x6.w;
    w = bhi(q.w); a0 += w*x7.x; a1 += w*x7.y; a2 += w*x7.z; a3 += w*x7.w;
  }
  *(float4*)(part + (wq * 64 + lane) * 4) = make_float4(a0, a1, a2, a3);
  __syncthreads();
  if (tid < 64) {
    const int jj = tid & 15, bb = tid >> 4;
    const int b = bg * 4 + bb, j = rg * 16 + jj;
    float g[4];
    #pragma unroll
    for (int gg = 0; gg < 4; ++gg) {
      const int l = gg * 16 + jj;
      g[gg] = part[(0*64+l)*4+bb] + part[(1*64+l)*4+bb]
            + part[(2*64+l)*4+bb] + part[(3*64+l)*4+bb] + d0b[gg * 256 + j];
    }
    float c = cl0[b * 256 + j], h;
    cellupd(g[0], g[1], g[2], g[3], c, h);
    cl0[b * 256 + j] = c;
    hl0w[b * 256 + j] = h;
  }
}

// K3 (cell1): K=512 over [hl0(t) | hl1(t-1)].
__global__ __launch_bounds__(256) void cell1_kernel(
    const float* __restrict__ hl0w, const float* __restrict__ hl1r,
    const unsigned short* __restrict__ d1p, const float* __restrict__ d1b,
    float* __restrict__ cl1, float* __restrict__ hl1w,
    float* __restrict__ dec_h, int t)
{
  const int blk = blockIdx.x, rg = blk & 15, bg = blk >> 4, tid = threadIdx.x;
  const int lane = tid & 63, wq = tid >> 6;
  __shared__ __align__(16) float xT[512 * 4];
  __shared__ __align__(16) float part[4 * 64 * 4];
  for (int i = tid; i < 2048; i += 256) {
    const int bb = i >> 9, k = i & 511;
    const int b = bg * 4 + bb;
    xT[k * 4 + bb] = (k < 256) ? hl0w[b * 256 + k] : hl1r[b * 256 + (k - 256)];
  }
  __syncthreads();
  const uint4* __restrict__ p = (const uint4*)d1p + ((size_t)rg * 64 + wq * 16) * 64 + lane;
  const float4* __restrict__ xp = (const float4*)xT + wq * 128;
  float a0 = 0.f, a1 = 0.f, a2 = 0.f, a3 = 0.f;
  #pragma unroll 4
  for (int kc = 0; kc < 16; ++kc) {
    const uint4 q = p[(size_t)kc * 64];
    const float4 x0 = xp[kc*8+0], x1 = xp[kc*8+1], x2 = xp[kc*8+2], x3 = xp[kc*8+3];
    const float4 x4 = xp[kc*8+4], x5 = xp[kc*8+5], x6 = xp[kc*8+6], x7 = xp[kc*8+7];
    float w;
    w = blo(q.x); a0 += w*x0.x; a1 += w*x0.y; a2 += w*x0.z; a3 += w*x0.w;
    w = bhi(q.x); a0 += w*x1.x; a1 += w*x1.y; a2 += w*x1.z; a3 += w*x1.w;
    w = blo(q.y); a0 += w*x2.x; a1 += w*x2.y; a2 += w*x2.z; a3 += w*x2.w;
    w = bhi(q.y); a0 += w*x3.x; a1 += w*x3.y; a2 += w*x3.z; a3 += w*x3.w;
    w = blo(q.z); a0 += w*x4.x; a1 += w*x4.y; a2 += w*x4.z; a3 += w*x4.w;
    w = bhi(q.z); a0 += w*x5.x; a1 += w*x5.y; a2 += w*x5.z; a3 += w*x5.w;
    w = blo(q.w); a0 += w*x6.x; a1 += w*x6.y; a2 += w*x6.z; a3 += w*x6.w;
    w = bhi(q.w); a0 += w*x7.x; a1 += w*x7.y; a2 += w*x7.z; a3 += w*x7.w;
  }
  *(float4*)(part + (wq * 64 + lane) * 4) = make_float4(a0, a1, a2, a3);
  __syncthreads();
  if (tid < 64) {
    const int jj = tid & 15, bb = tid >> 4;
    const int b = bg * 4 + bb, j = rg * 16 + jj;
    float g[4];
    #pragma unroll
    for (int gg = 0; gg < 4; ++gg) {
      const int l = gg * 16 + jj;
      g[gg] = part[(0*64+l)*4+bb] + part[(1*64+l)*4+bb]
            + part[(2*64+l)*4+bb] + part[(3*64+l)*4+bb] + d1b[gg * 256 + j];
    }
    float c = cl1[b * 256 + j], h;
    cellupd(g[0], g[1], g[2], g[3], c, h);
    cl1[b * 256 + j] = c;
    hl1w[b * 256 + j] = h;
    dec_h[((size_t)b * T_ + t) * H_ + j] = h;
  }
}

// out (unchanged)
__global__ __launch_bounds__(256) void out_kernel(
    const float* __restrict__ dec_h, const unsigned short* __restrict__ emb_s,
    void* __restrict__ out, const int* __restrict__ flagp)
{
  __shared__ __align__(16) float hs[16 * 256];
  const int blk = blockIdx.x, tid = threadIdx.x;
  const int isf32 = *flagp;
  const float* srcp = dec_h + (size_t)blk * (16 * 256);
  for (int i = tid; i < 16 * 256; i += 256) hs[i] = srcp[i];
  __syncthreads();
  #pragma unroll
  for (int vi = 0; vi < 4; ++vi) {
    const int v = tid + vi * 256;
    if (v < V_) {
      const uint4* p = (const uint4*)emb_s + (size_t)(v >> 6) * 32 * 64 + (v & 63);
      float acc[16];
      #pragma unroll
      for (int r = 0; r < 16; ++r) acc[r] = 0.0f;
      for (int kc = 0; kc < 32; ++kc) {
        const uint4 q = p[(size_t)kc * 64];
        const float w0=blo(q.x), w1=bhi(q.x), w2=blo(q.y), w3=bhi(q.y),
                    w4=blo(q.z), w5=bhi(q.z), w6=blo(q.w), w7=bhi(q.w);
        #pragma unroll
        for (int r = 0; r < 16; ++r) {
          const float4 x0 = *(const float4*)(hs + r * 256 + kc * 8);
          const float4 x1 = *(const float4*)(hs + r * 256 + kc * 8 + 4);
          acc[r] += w0*x0.x + w1*x0.y + w2*x0.z + w3*x0.w + w4*x1.x + w5*x1.y + w6*x1.z + w7*x1.w;
        }
      }
      const size_t rowbase = (size_t)blk * 16;
      if (isf32) {
        float* o = (float*)out;
        #pragma unroll
        for (int r = 0; r < 16; ++r) o[(rowbase + r) * V_ + v] = acc[r];
      } else {
        __hip_bfloat16* o = (__hip_bfloat16*)out;
        #pragma unroll
        for (int r = 0; r < 16; ++r) o[(rowbase + r) * V_ + v] = __float2bfloat16(acc[r]);
      }
    }
  }
}

extern "C" void kernel_launch(void* const* d_in, const int* in_sizes, int n_in,
                              void* d_out, int out_size, void* d_ws, size_t ws_size,
                              hipStream_t stream)
{
  (void)in_sizes; (void)n_in; (void)out_size; (void)ws_size;
  const int* src = (const int*)d_in[0];
  const int* tgt = (const int*)d_in[1];

  char* base = (char*)d_ws;
  int* flag = (int*)base;
  float* ws = (float*)(base + 256);
  size_t off = 0;
  float* f0      = ws + off; off += (size_t)B_ * S_ * H_;
  float* b0      = ws + off; off += (size_t)B_ * S_ * H_;
  float* enc_out = ws + off; off += (size_t)B_ * S_ * 2 * H_;
  float* hcbuf   = ws + off; off += 4 * (size_t)B_ * H_;
  float* h0c0    = ws + off; off += 2 * (size_t)B_ * H_;
  float* emb_f   = ws + off; off += (size_t)V_ * D_;
  float* e_sc    = ws + off; off += (size_t)B_ * S_;
  float* ctxb    = ws + off; off += (size_t)B_ * 512;
  float* hl0A    = ws + off; off += (size_t)B_ * H_;
  float* hl0B    = ws + off; off += (size_t)B_ * H_;
  float* hl1A    = ws + off; off += (size_t)B_ * H_;
  float* hl1B    = ws + off; off += (size_t)B_ * H_;
  float* cl0     = ws + off; off += (size_t)B_ * H_;
  float* cl1     = ws + off; off += (size_t)B_ * H_;
  float* e0f_b   = ws + off; off += 1024;
  float* e0b_b   = ws + off; off += 1024;
  float* e1f_b   = ws + off; off += 1024;
  float* e1b_b   = ws + off; off += 1024;
  float* d0_b    = ws + off; off += 1024;
  float* d1_b    = ws + off; off += 1024;
  float* hpb_f   = ws + off; off += 256;
  float* cpb_f   = ws + off; off += 256;
  float* attv_f  = ws + off; off += 256;
  unsigned short* us = (unsigned short*)(ws + off);
  size_t uo = 0;
  unsigned short* e0f_s  = us + uo; uo += (size_t)1024 * 512;
  unsigned short* e0b_s  = us + uo; uo += (size_t)1024 * 512;
  unsigned short* e1f_s  = us + uo; uo += (size_t)1024 * 768;
  unsigned short* e1b_s  = us + uo; uo += (size_t)1024 * 768;
  unsigned short* d0p_s  = us + uo; uo += (size_t)1024 * 1024;
  unsigned short* d1p_s  = us + uo; uo += (size_t)1024 * 512;
  unsigned short* wdec_s = us + uo; uo += (size_t)256 * 256;
  unsigned short* wenc_s = us + uo; uo += (size_t)256 * 512;
  unsigned short* hpw_s  = us + uo; uo += (size_t)256 * 512;
  unsigned short* cpw_s  = us + uo; uo += (size_t)256 * 512;
  unsigned short* emb_s  = us + uo; uo += (size_t)1024 * 256;
  float* dec_h = f0;
  float* epT   = b0;

  hipLaunchKernelGGL(probe_kernel, dim3(1), dim3(64), 0, stream,
                     (const unsigned short*)d_in[3], flag);

  auto swz = [&](int idx, unsigned short* dst, int R, int Ks, int Kt, int c0, int perm){
    const int n = R * Ks;
    hipLaunchKernelGGL(swzb_kernel, dim3((n + 255) / 256), dim3(256), 0, stream,
                       d_in[idx], dst, R, Ks, Kt, c0, perm, flag);
  };
  auto bias2 = [&](int ia, int ib, float* dst, int n){
    hipLaunchKernelGGL(bias_kernel, dim3((n + 255) / 256), dim3(256), 0, stream,
                       d_in[ia], d_in[ib], dst, n, flag);
  };

  hipLaunchKernelGGL(conv_kernel, dim3((V_ * D_ + 255) / 256), dim3(256), 0, stream,
                     d_in[2], emb_f, V_ * D_, flag);
  hipLaunchKernelGGL(conv_kernel, dim3(1), dim3(256), 0, stream, d_in[28], hpb_f, 256, flag);
  hipLaunchKernelGGL(conv_kernel, dim3(1), dim3(256), 0, stream, d_in[30], cpb_f, 256, flag);
  hipLaunchKernelGGL(conv_kernel, dim3(1), dim3(256), 0, stream, d_in[33], attv_f, 256, flag);
  bias2(5, 6, e0f_b, 1024);   bias2(9, 10, e0b_b, 1024);
  bias2(13, 14, e1f_b, 1024); bias2(17, 18, e1b_b, 1024);
  bias2(21, 22, d0_b, 1024);  bias2(25, 26, d1_b, 1024);
  swz(3,  e0f_s, 1024, 256, 512, 0, 0);   swz(4,  e0f_s, 1024, 256, 512, 256, 0);
  swz(7,  e0b_s, 1024, 256, 512, 0, 0);   swz(8,  e0b_s, 1024, 256, 512, 256, 0);
  swz(11, e1f_s, 1024, 512, 768, 0, 0);   swz(12, e1f_s, 1024, 256, 768, 512, 0);
  swz(15, e1b_s, 1024, 512, 768, 0, 0);   swz(16, e1b_s, 1024, 256, 768, 512, 0);
  swz(19, d0p_s, 1024, 768, 1024, 0, 1);  swz(20, d0p_s, 1024, 256, 1024, 768, 1);
  swz(23, d1p_s, 1024, 256, 512, 0, 1);   swz(24, d1p_s, 1024, 256, 512, 256, 1);
  swz(32, wdec_s, 256, 256, 256, 0, 0);
  swz(31, wenc_s, 256, 512, 512, 0, 0);
  swz(27, hpw_s, 256, 512, 512, 0, 0);
  swz(29, cpw_s, 256, 512, 512, 0, 0);
  swz(2,  emb_s, 1000, 256, 256, 0, 0);

  hipLaunchKernelGGL(enc0_kernel, dim3(128), dim3(1024), 0, stream,
                     src, emb_f, e0f_s, e0b_s, e0f_b, e0b_b, f0, b0);
  hipLaunchKernelGGL(enc1_kernel, dim3(128), dim3(1024), 0, stream,
                     f0, b0, e1f_s, e1b_s, e1f_b, e1b_b, enc_out, hcbuf);
  hipLaunchKernelGGL(proj_kernel, dim3(1088), dim3(256), 0, stream,
                     enc_out, hcbuf, wenc_s, hpw_s, cpw_s, hpb_f, cpb_f, epT, h0c0);
  hipLaunchKernelGGL(dec_init_kernel, dim3(64), dim3(256), 0, stream,
                     h0c0, hl0A, hl1A, cl0, cl1);

  for (int t = 0; t < T_; ++t) {
    float* hl0r = (t & 1) ? hl0B : hl0A;
    float* hl0w = (t & 1) ? hl0A : hl0B;
    float* hl1r = (t & 1) ? hl1B : hl1A;
    float* hl1w = (t & 1) ? hl1A : hl1B;
    hipLaunchKernelGGL(att_score_kernel, dim3(256), dim3(256), 0, stream,
                       hl1r, wdec_s, epT, attv_f, src, e_sc);
    hipLaunchKernelGGL(att_ctx_kernel, dim3(256), dim3(256), 0, stream,
                       e_sc, enc_out, ctxb);
    hipLaunchKernelGGL(cell0_kernel, dim3(256), dim3(256), 0, stream,
                       tgt, emb_f, ctxb, hl0r, d0p_s, d0_b, cl0, hl0w, t);
    hipLaunchKernelGGL(cell1_kernel, dim3(256), dim3(256), 0, stream,
                       hl0w, hl1r, d1p_s, d1_b, cl1, hl1w, dec_h, t);
  }

  hipLaunchKernelGGL(out_kernel, dim3(1024), dim3(256), 0, stream,
                     dec_h, emb_s, d_out, flag);
}